// Round 5
// baseline (693.213 us; speedup 1.0000x reference)
//
#include <hip/hip_runtime.h>
#include <hip/hip_bf16.h>

typedef __hip_bfloat16 bf16;
typedef __bf16 bf16x8 __attribute__((ext_vector_type(8)));
typedef float f32x4 __attribute__((ext_vector_type(4)));
typedef short short8 __attribute__((ext_vector_type(8)));

#define NH 24
#define NKV 8
#define HD 128
#define SEQ 2048
#define NREP 3

__device__ inline void gload16(const void* g, void* l) {
  __builtin_amdgcn_global_load_lds(
      (const __attribute__((address_space(1))) void*)g,
      (__attribute__((address_space(3))) void*)l, 16, 0, 0);
}

// ---------------- cast f32 -> bf16 (vectorized) ----------------
__global__ void cast_f32_bf16(const float* __restrict__ in, bf16* __restrict__ out, int n4) {
  int i = blockIdx.x * 256 + threadIdx.x;
  if (i >= n4) return;
  float4 v = reinterpret_cast<const float4*>(in)[i];
  ushort4 u;
  u.x = __builtin_bit_cast(unsigned short, __float2bfloat16(v.x));
  u.y = __builtin_bit_cast(unsigned short, __float2bfloat16(v.y));
  u.z = __builtin_bit_cast(unsigned short, __float2bfloat16(v.z));
  u.w = __builtin_bit_cast(unsigned short, __float2bfloat16(v.w));
  reinterpret_cast<ushort4*>(out)[i] = u;
}

// ---------------- transpose + cast: W (KxN f32) -> WT (NxK bf16) ----------------
__global__ void transpose_cast(const float* __restrict__ W, bf16* __restrict__ WT, int K, int N) {
  __shared__ bf16 tile[32][33];
  int n0 = blockIdx.x * 32, k0 = blockIdx.y * 32;
  int tx = threadIdx.x, ty = threadIdx.y;  // (32, 8)
#pragma unroll
  for (int i = 0; i < 4; ++i) {
    int kl = ty + i * 8;
    tile[kl][tx] = __float2bfloat16(W[(size_t)(k0 + kl) * N + n0 + tx]);
  }
  __syncthreads();
#pragma unroll
  for (int i = 0; i < 4; ++i) {
    int nl = ty + i * 8;
    WT[(size_t)(n0 + nl) * K + k0 + tx] = tile[tx][nl];
  }
}

// ---------------- V global transpose: Vb (b*S rows, g*HD cols) -> Vt[b][g][d][s] ----------------
__global__ void transpose_v(const bf16* __restrict__ Vb, bf16* __restrict__ Vt) {
  __shared__ bf16 tile[32][33];
  int bg = blockIdx.z;
  int b = bg >> 3, g = bg & 7;
  int s0 = blockIdx.x * 32, d0 = blockIdx.y * 32;
  int tx = threadIdx.x, ty = threadIdx.y;  // (32, 8)
#pragma unroll
  for (int i = 0; i < 4; ++i) {
    int sl = ty + i * 8;
    tile[sl][tx] = Vb[(size_t)(b * SEQ + s0 + sl) * (NKV * HD) + g * HD + d0 + tx];
  }
  __syncthreads();
#pragma unroll
  for (int i = 0; i < 4; ++i) {
    int dl = ty + i * 8;
    Vt[((size_t)(b * NKV + g) * HD + d0 + dl) * SEQ + s0 + tx] = tile[tx][dl];
  }
}

// ---------------- RoPE in-place on bf16 buffer ----------------
__global__ void rope_kernel(bf16* __restrict__ T, const float* __restrict__ cosT,
                            const float* __restrict__ sinT, int H, int total) {
  int i = blockIdx.x * 256 + threadIdx.x;
  if (i >= total) return;
  int d2 = i & 63;
  int rh = i >> 6;
  int r = rh / H;
  int s = r & (SEQ - 1);
  float c = cosT[s * 64 + d2];
  float sn = sinT[s * 64 + d2];
  bf16* p = T + (size_t)rh * HD + d2 * 2;
  float a = __bfloat162float(p[0]);
  float b = __bfloat162float(p[1]);
  p[0] = __float2bfloat16(a * c - b * sn);
  p[1] = __float2bfloat16(a * sn + b * c);
}

// ---------------- GEMM: C[M,N] = A[M,K] @ BT[N,K]^T  (m97-style) ----------------
template <bool OUT_BF16>
__global__ __launch_bounds__(256) void gemm_bt(const bf16* __restrict__ A,
                                               const bf16* __restrict__ BT,
                                               void* __restrict__ Cv,
                                               int M, int N, int K) {
  __shared__ bf16 lsA[128 * 32];
  __shared__ bf16 lsB[128 * 32];
  int m0 = blockIdx.y * 128, n0 = blockIdx.x * 128;
  int tid = threadIdx.x;
  int w = tid >> 6, lane = tid & 63;
  int wm = w >> 1, wn = w & 1;
  int lr = lane & 15, lk = lane >> 4;
  f32x4 acc[4][4] = {};
  for (int k0 = 0; k0 < K; k0 += 32) {
    __syncthreads();
#pragma unroll
    for (int is = 0; is < 2; ++is) {
      int slot = is * 256 + tid;
      int row = slot >> 2, kc = slot & 3;
      gload16(A + (size_t)(m0 + row) * K + k0 + kc * 8, lsA + slot * 8);
      gload16(BT + (size_t)(n0 + row) * K + k0 + kc * 8, lsB + slot * 8);
    }
    __syncthreads();
    bf16x8 aF[4], bF[4];
#pragma unroll
    for (int t = 0; t < 4; ++t) {
      aF[t] = *reinterpret_cast<const bf16x8*>(&lsA[(wm * 64 + t * 16 + lr) * 32 + lk * 8]);
      bF[t] = *reinterpret_cast<const bf16x8*>(&lsB[(wn * 64 + t * 16 + lr) * 32 + lk * 8]);
    }
#pragma unroll
    for (int mt = 0; mt < 4; ++mt)
#pragma unroll
      for (int nt = 0; nt < 4; ++nt)
        acc[mt][nt] = __builtin_amdgcn_mfma_f32_16x16x32_bf16(aF[mt], bF[nt], acc[mt][nt], 0, 0, 0);
  }
#pragma unroll
  for (int mt = 0; mt < 4; ++mt)
#pragma unroll
    for (int nt = 0; nt < 4; ++nt)
#pragma unroll
      for (int r = 0; r < 4; ++r) {
        int m = m0 + wm * 64 + mt * 16 + lk * 4 + r;
        int n = n0 + wn * 64 + nt * 16 + lr;
        float v = acc[mt][nt][r];
        if (OUT_BF16)
          reinterpret_cast<bf16*>(Cv)[(size_t)m * N + n] = __float2bfloat16(v);
        else
          reinterpret_cast<float*>(Cv)[(size_t)m * N + n] = v;
      }
}

// ---------------- Flash attention (causal, GQA, 3 heads/block) ----------------
// 4 waves x 16 q-rows = 64 q-rows/block; KV tile = 64 rows; all NREP=3 heads of one
// KV group processed per block (shared K/V staging, 3x work per tile).
// Klds: [64 s][16 chunks of 8 bf16], chunk XOR-swizzled by (s&7)  (both-sides swizzle)
// Vlds: [128 d][8 chunks of 8 bf16 (s)], chunk XOR-swizzled by (d&7)
// Plds: per-wave [16 q][8 chunks of 8 bf16 (k)], chunk XOR-swizzled by (q&7)
#define SCALE_LOG2 0.12751745f  // (1/sqrt(128)) * log2(e)

__global__ __launch_bounds__(256, 2) void attn_kernel(const bf16* __restrict__ Q,
                                                      const bf16* __restrict__ K,
                                                      const bf16* __restrict__ Vt,
                                                      bf16* __restrict__ O) {
  __shared__ bf16 Klds[64 * 128];      // 16 KB
  __shared__ bf16 Vlds[128 * 64];      // 16 KB
  __shared__ bf16 Plds[4][16 * 64];    // 8 KB
  int qt = (int)gridDim.x - 1 - (int)blockIdx.x;   // big-work blocks first
  int bg = blockIdx.y;                 // b*NKV + g
  int b = bg >> 3, g = bg & 7;
  int tid = threadIdx.x, w = tid >> 6, lane = tid & 63;
  int lr = lane & 15, lk = lane >> 4;
  int q0 = qt * 64 + w * 16;  // wave's q base

  // --- Q fragments for 3 heads (A operand): rows q0+lr, k = kk*32 + lk*8 + j ---
  bf16x8 aQ[3][4];
#pragma unroll
  for (int ht = 0; ht < 3; ++ht) {
    const bf16* qrow =
        Q + ((size_t)(b * SEQ) + q0 + lr) * (NH * HD) + (g * NREP + ht) * HD;
#pragma unroll
    for (int kk = 0; kk < 4; ++kk)
      aQ[ht][kk] = *reinterpret_cast<const bf16x8*>(qrow + kk * 32 + lk * 8);
  }

  // --- staging offsets (tile-independent) ---
  const bf16* kvK = K + ((size_t)b * SEQ * NKV + g) * HD;
  const bf16* kvVt = Vt + ((size_t)(b * NKV + g) * HD) * SEQ;
  int koff[4];
  bf16* kdst[4];
#pragma unroll
  for (int i = 0; i < 4; ++i) {
    int t = i * 256 + tid;          // 1024 K slots of 8 bf16
    int row = t >> 4, c = t & 15;
    int sc = c ^ (row & 7);         // pre-swizzled source chunk
    koff[i] = row * (NKV * HD) + sc * 8;
    kdst[i] = Klds + t * 8;
  }
  int voff[4];
  bf16* vdst[4];
#pragma unroll
  for (int i = 0; i < 4; ++i) {
    int t = i * 256 + tid;          // 1024 V slots of 8 bf16
    int d = t >> 3, c = t & 7;
    int sc = c ^ (d & 7);
    voff[i] = d * SEQ + sc * 8;
    vdst[i] = Vlds + t * 8;
  }

  f32x4 Oacc[3][8] = {};
  float m_s[3][4], l_s[3][4];
#pragma unroll
  for (int ht = 0; ht < 3; ++ht)
#pragma unroll
    for (int r = 0; r < 4; ++r) { m_s[ht][r] = -1e30f; l_s[ht][r] = 0.f; }

  bf16* pb = Plds[w];

  int jlast = qt * 64;
  for (int j0 = 0; j0 <= jlast; j0 += 64) {
    __syncthreads();  // prev-tile readers done
    {
      const bf16* ks = kvK + (size_t)j0 * (NKV * HD);
      const bf16* vs = kvVt + j0;
#pragma unroll
      for (int i = 0; i < 4; ++i) gload16(ks + koff[i], kdst[i]);
#pragma unroll
      for (int i = 0; i < 4; ++i) gload16(vs + voff[i], vdst[i]);
    }
    __syncthreads();  // staging complete (barrier drains vmcnt)
    if (j0 > q0 + 15) continue;

#pragma unroll
    for (int ht = 0; ht < 3; ++ht) {
      // ---- QK^T : 4 n-tiles of 16 cols ----
      f32x4 sc4[4] = {};
#pragma unroll
      for (int kk = 0; kk < 4; ++kk) {
#pragma unroll
        for (int nt = 0; nt < 4; ++nt) {
          int jrow = nt * 16 + lr;
          int pos = (4 * kk + lk) ^ (lr & 7);
          bf16x8 bK = *reinterpret_cast<const bf16x8*>(&Klds[jrow * 128 + pos * 8]);
          sc4[nt] = __builtin_amdgcn_mfma_f32_16x16x32_bf16(aQ[ht][kk], bK, sc4[nt], 0, 0, 0);
        }
      }

      // ---- mask + online softmax (log2 domain) ----
      float sv[4][4], mx[4];
#pragma unroll
      for (int r = 0; r < 4; ++r) mx[r] = -3e38f;
#pragma unroll
      for (int nt = 0; nt < 4; ++nt) {
        int col = j0 + nt * 16 + lr;
#pragma unroll
        for (int r = 0; r < 4; ++r) {
          int row = q0 + lk * 4 + r;
          sv[nt][r] = (col > row) ? -3e38f : sc4[nt][r] * SCALE_LOG2;
          mx[r] = fmaxf(mx[r], sv[nt][r]);
        }
      }
#pragma unroll
      for (int d = 1; d < 16; d <<= 1)
#pragma unroll
        for (int r = 0; r < 4; ++r) mx[r] = fmaxf(mx[r], __shfl_xor(mx[r], d, 64));

      // exact defer-max: rescale only if some row's max grew
      bool grow = false;
#pragma unroll
      for (int r = 0; r < 4; ++r) grow = grow || (mx[r] > m_s[ht][r]);
      if (__any(grow)) {
        float alpha[4];
#pragma unroll
        for (int r = 0; r < 4; ++r) {
          float mn = fmaxf(m_s[ht][r], mx[r]);
          alpha[r] = exp2f(m_s[ht][r] - mn);
          m_s[ht][r] = mn;
          l_s[ht][r] *= alpha[r];
        }
#pragma unroll
        for (int nc = 0; nc < 8; ++nc)
#pragma unroll
          for (int r = 0; r < 4; ++r) Oacc[ht][nc][r] *= alpha[r];
      }
      float p[4][4], rs[4];
#pragma unroll
      for (int r = 0; r < 4; ++r) {
        rs[r] = 0.f;
#pragma unroll
        for (int nt = 0; nt < 4; ++nt) {
          p[nt][r] = exp2f(sv[nt][r] - m_s[ht][r]);
          rs[r] += p[nt][r];
        }
      }
#pragma unroll
      for (int d = 1; d < 16; d <<= 1)
#pragma unroll
        for (int r = 0; r < 4; ++r) rs[r] += __shfl_xor(rs[r], d, 64);
#pragma unroll
      for (int r = 0; r < 4; ++r) l_s[ht][r] += rs[r];

      // ---- P -> wave-private swizzled LDS ----
#pragma unroll
      for (int nt = 0; nt < 4; ++nt)
#pragma unroll
        for (int r = 0; r < 4; ++r) {
          int row = lk * 4 + r;
          int c = nt * 16 + lr;
          pb[row * 64 + (((c >> 3) ^ (row & 7)) * 8) + (c & 7)] = __float2bfloat16(p[nt][r]);
        }
      asm volatile("s_waitcnt lgkmcnt(0)" ::: "memory");
      __builtin_amdgcn_sched_barrier(0);

      // ---- O += P @ V  (V fragments: contiguous bf16x8 along s from Vlds) ----
#pragma unroll
      for (int kb = 0; kb < 2; ++kb) {
        int px = ((kb * 4 + lk) ^ (lr & 7)) * 8;
        bf16x8 aP = *reinterpret_cast<const bf16x8*>(&pb[lr * 64 + px]);
#pragma unroll
        for (int nc = 0; nc < 8; ++nc) {
          bf16x8 bV = *reinterpret_cast<const bf16x8*>(&Vlds[(nc * 16 + lr) * 64 + px]);
          Oacc[ht][nc] = __builtin_amdgcn_mfma_f32_16x16x32_bf16(aP, bV, Oacc[ht][nc], 0, 0, 0);
        }
      }
    }
  }

  // ---- epilogue ----
#pragma unroll
  for (int ht = 0; ht < 3; ++ht)
#pragma unroll
    for (int r = 0; r < 4; ++r) {
      float inv = 1.0f / l_s[ht][r];
      size_t rowoff =
          ((size_t)(b * SEQ) + q0 + lk * 4 + r) * (NH * HD) + (g * NREP + ht) * HD;
#pragma unroll
      for (int nc = 0; nc < 8; ++nc)
        O[rowoff + nc * 16 + lr] = __float2bfloat16(Oacc[ht][nc][r] * inv);
    }
}

extern "C" void kernel_launch(void* const* d_in, const int* in_sizes, int n_in,
                              void* d_out, int out_size, void* d_ws, size_t ws_size,
                              hipStream_t stream) {
  const float* x = (const float*)d_in[0];
  const float* wq = (const float*)d_in[1];
  const float* wk = (const float*)d_in[2];
  const float* wv = (const float*)d_in[3];
  const float* wo = (const float*)d_in[4];
  const float* fc = (const float*)d_in[5];
  const float* fs = (const float*)d_in[6];
  float* out = (float*)d_out;
  (void)in_sizes; (void)n_in; (void)out_size; (void)ws_size;

  const int R = 2 * SEQ;
  const int DIMc = 3072;
  const int NQ = NH * HD;
  const int NKd = NKV * HD;

  char* ws = (char*)d_ws;
  bf16* xb = (bf16*)ws;   ws += (size_t)R * DIMc * 2;
  bf16* wqT = (bf16*)ws;  ws += (size_t)NQ * DIMc * 2;
  bf16* wkT = (bf16*)ws;  ws += (size_t)NKd * DIMc * 2;
  bf16* wvT = (bf16*)ws;  ws += (size_t)NKd * DIMc * 2;
  bf16* woT = (bf16*)ws;  ws += (size_t)DIMc * NQ * 2;
  bf16* Qb = (bf16*)ws;   ws += (size_t)R * NQ * 2;
  bf16* Kb = (bf16*)ws;   ws += (size_t)R * NKd * 2;
  bf16* Vb = (bf16*)ws;   ws += (size_t)R * NKd * 2;
  bf16* Ob = (bf16*)ws;   ws += (size_t)R * NQ * 2;
  bf16* VtG = xb;  // aliases xb: xb is dead after the V projection GEMM

  {
    int n4 = R * DIMc / 4;
    cast_f32_bf16<<<n4 / 256, 256, 0, stream>>>(x, xb, n4);
  }
  transpose_cast<<<dim3(NQ / 32, DIMc / 32), dim3(32, 8), 0, stream>>>(wq, wqT, DIMc, NQ);
  transpose_cast<<<dim3(NKd / 32, DIMc / 32), dim3(32, 8), 0, stream>>>(wk, wkT, DIMc, NKd);
  transpose_cast<<<dim3(NKd / 32, DIMc / 32), dim3(32, 8), 0, stream>>>(wv, wvT, DIMc, NKd);
  transpose_cast<<<dim3(DIMc / 32, NQ / 32), dim3(32, 8), 0, stream>>>(wo, woT, NQ, DIMc);
  gemm_bt<true><<<dim3(NQ / 128, R / 128), 256, 0, stream>>>(xb, wqT, Qb, R, NQ, DIMc);
  gemm_bt<true><<<dim3(NKd / 128, R / 128), 256, 0, stream>>>(xb, wkT, Kb, R, NKd, DIMc);
  gemm_bt<true><<<dim3(NKd / 128, R / 128), 256, 0, stream>>>(xb, wvT, Vb, R, NKd, DIMc);
  // V -> Vt[b][g][d][s]  (xb region; xb no longer needed)
  transpose_v<<<dim3(SEQ / 32, HD / 32, 2 * NKV), dim3(32, 8), 0, stream>>>(Vb, VtG);
  {
    int totQ = R * NH * 64;
    rope_kernel<<<totQ / 256, 256, 0, stream>>>(Qb, fc, fs, NH, totQ);
    int totK = R * NKV * 64;
    rope_kernel<<<totK / 256, 256, 0, stream>>>(Kb, fc, fs, NKV, totK);
  }
  attn_kernel<<<dim3(SEQ / 64, 2 * NKV), 256, 0, stream>>>(Qb, Kb, VtG, Ob);
  gemm_bt<false><<<dim3(DIMc / 128, R / 128), 256, 0, stream>>>(Ob, woT, out, R, DIMc, NQ);
}

// Round 6
// 519.126 us; speedup vs baseline: 1.3353x; 1.3353x over previous
//
#include <hip/hip_runtime.h>
#include <hip/hip_bf16.h>

typedef __hip_bfloat16 bf16;
typedef __bf16 bf16x8 __attribute__((ext_vector_type(8)));
typedef float f32x4 __attribute__((ext_vector_type(4)));
typedef short short8 __attribute__((ext_vector_type(8)));

#define NH 24
#define NKV 8
#define HD 128
#define SEQ 2048
#define NREP 3
#define QKVD 5120              // fused QKV row stride (3072 + 1024 + 1024)
#define KOFF 3072              // K region offset in fused row
#define VOFF 4096              // V region offset in fused row

__device__ inline void gload16(const void* g, void* l) {
  __builtin_amdgcn_global_load_lds(
      (const __attribute__((address_space(1))) void*)g,
      (__attribute__((address_space(3))) void*)l, 16, 0, 0);
}

// ---------------- cast f32 -> bf16 (vectorized) ----------------
__global__ void cast_f32_bf16(const float* __restrict__ in, bf16* __restrict__ out, int n4) {
  int i = blockIdx.x * 256 + threadIdx.x;
  if (i >= n4) return;
  float4 v = reinterpret_cast<const float4*>(in)[i];
  ushort4 u;
  u.x = __builtin_bit_cast(unsigned short, __float2bfloat16(v.x));
  u.y = __builtin_bit_cast(unsigned short, __float2bfloat16(v.y));
  u.z = __builtin_bit_cast(unsigned short, __float2bfloat16(v.z));
  u.w = __builtin_bit_cast(unsigned short, __float2bfloat16(v.w));
  reinterpret_cast<ushort4*>(out)[i] = u;
}

// ---------------- transpose + cast: W (KxN f32) -> WT (NxK bf16) ----------------
__global__ void transpose_cast(const float* __restrict__ W, bf16* __restrict__ WT, int K, int N) {
  __shared__ bf16 tile[32][33];
  int n0 = blockIdx.x * 32, k0 = blockIdx.y * 32;
  int tx = threadIdx.x, ty = threadIdx.y;  // (32, 8)
#pragma unroll
  for (int i = 0; i < 4; ++i) {
    int kl = ty + i * 8;
    tile[kl][tx] = __float2bfloat16(W[(size_t)(k0 + kl) * N + n0 + tx]);
  }
  __syncthreads();
#pragma unroll
  for (int i = 0; i < 4; ++i) {
    int nl = ty + i * 8;
    WT[(size_t)(n0 + nl) * K + k0 + tx] = tile[tx][nl];
  }
}

// ---------------- V global transpose: QKV V-region -> Vt[b][g][d][s] ----------------
__global__ void transpose_v(const bf16* __restrict__ Vsrc, bf16* __restrict__ Vt) {
  __shared__ bf16 tile[32][33];
  int bg = blockIdx.z;
  int b = bg >> 3, g = bg & 7;
  int s0 = blockIdx.x * 32, d0 = blockIdx.y * 32;
  int tx = threadIdx.x, ty = threadIdx.y;  // (32, 8)
#pragma unroll
  for (int i = 0; i < 4; ++i) {
    int sl = ty + i * 8;
    tile[sl][tx] = Vsrc[(size_t)(b * SEQ + s0 + sl) * QKVD + g * HD + d0 + tx];
  }
  __syncthreads();
#pragma unroll
  for (int i = 0; i < 4; ++i) {
    int dl = ty + i * 8;
    Vt[((size_t)(b * NKV + g) * HD + d0 + dl) * SEQ + s0 + tx] = tile[tx][dl];
  }
}

// ---------------- RoPE in-place (generalized row stride) ----------------
__global__ void rope_kernel(bf16* __restrict__ T, const float* __restrict__ cosT,
                            const float* __restrict__ sinT, int H, int stride, int total) {
  int i = blockIdx.x * 256 + threadIdx.x;
  if (i >= total) return;
  int d2 = i & 63;
  int rh = i >> 6;
  int r = rh / H;
  int h = rh - r * H;
  int s = r & (SEQ - 1);
  float c = cosT[s * 64 + d2];
  float sn = sinT[s * 64 + d2];
  bf16* p = T + (size_t)r * stride + h * HD + d2 * 2;
  float a = __bfloat162float(p[0]);
  float b = __bfloat162float(p[1]);
  p[0] = __float2bfloat16(a * c - b * sn);
  p[1] = __float2bfloat16(a * sn + b * c);
}

// ---------------- GEMM: C[M,N] = A[M,K] @ BT[N,K]^T  (m97-style) ----------------
template <bool OUT_BF16>
__global__ __launch_bounds__(256) void gemm_bt(const bf16* __restrict__ A,
                                               const bf16* __restrict__ BT,
                                               void* __restrict__ Cv,
                                               int M, int N, int K) {
  __shared__ bf16 lsA[128 * 32];
  __shared__ bf16 lsB[128 * 32];
  int m0 = blockIdx.y * 128, n0 = blockIdx.x * 128;
  int tid = threadIdx.x;
  int w = tid >> 6, lane = tid & 63;
  int wm = w >> 1, wn = w & 1;
  int lr = lane & 15, lk = lane >> 4;
  f32x4 acc[4][4] = {};
  for (int k0 = 0; k0 < K; k0 += 32) {
    __syncthreads();
#pragma unroll
    for (int is = 0; is < 2; ++is) {
      int slot = is * 256 + tid;
      int row = slot >> 2, kc = slot & 3;
      gload16(A + (size_t)(m0 + row) * K + k0 + kc * 8, lsA + slot * 8);
      gload16(BT + (size_t)(n0 + row) * K + k0 + kc * 8, lsB + slot * 8);
    }
    __syncthreads();
    bf16x8 aF[4], bF[4];
#pragma unroll
    for (int t = 0; t < 4; ++t) {
      aF[t] = *reinterpret_cast<const bf16x8*>(&lsA[(wm * 64 + t * 16 + lr) * 32 + lk * 8]);
      bF[t] = *reinterpret_cast<const bf16x8*>(&lsB[(wn * 64 + t * 16 + lr) * 32 + lk * 8]);
    }
#pragma unroll
    for (int mt = 0; mt < 4; ++mt)
#pragma unroll
      for (int nt = 0; nt < 4; ++nt)
        acc[mt][nt] = __builtin_amdgcn_mfma_f32_16x16x32_bf16(aF[mt], bF[nt], acc[mt][nt], 0, 0, 0);
  }
#pragma unroll
  for (int mt = 0; mt < 4; ++mt)
#pragma unroll
    for (int nt = 0; nt < 4; ++nt)
#pragma unroll
      for (int r = 0; r < 4; ++r) {
        int m = m0 + wm * 64 + mt * 16 + lk * 4 + r;
        int n = n0 + wn * 64 + nt * 16 + lr;
        float v = acc[mt][nt][r];
        if (OUT_BF16)
          reinterpret_cast<bf16*>(Cv)[(size_t)m * N + n] = __float2bfloat16(v);
        else
          reinterpret_cast<float*>(Cv)[(size_t)m * N + n] = v;
      }
}

// ---------------- Flash attention (causal, GQA, balanced q-tile pairs) ----------------
// Each block processes q-tiles {blockIdx.x, NT-1-blockIdx.x} sequentially -> uniform
// 34 KV-tiles/block, zero tail. 4 waves x 16 q-rows; KV tile = 64 rows.
// Klds: [64 s][16 chunks of 8 bf16], chunk XOR-swizzled by (s&7)
// Vlds: [128 d][8 chunks of 8 bf16 (s)], chunk XOR-swizzled by (d&7)
// Plds: per-wave [16 q][8 chunks], chunk XOR-swizzled by (q&7)
#define SCALE_LOG2 0.12751745f  // (1/sqrt(128)) * log2(e)

__global__ __launch_bounds__(256, 3) void attn_kernel(const bf16* __restrict__ QKV,
                                                      const bf16* __restrict__ Vt,
                                                      bf16* __restrict__ O) {
  __shared__ bf16 Klds[64 * 128];      // 16 KB
  __shared__ bf16 Vlds[128 * 64];      // 16 KB
  __shared__ bf16 Plds[4][16 * 64];    // 8 KB
  int bh = blockIdx.y;
  int b = bh / NH, h = bh % NH, g = h / NREP;
  int tid = threadIdx.x, w = tid >> 6, lane = tid & 63;
  int lr = lane & 15, lk = lane >> 4;
  const int NT = SEQ / 64;

  // --- staging offsets (tile-independent) ---
  const bf16* kvK = QKV + ((size_t)b * SEQ) * QKVD + KOFF + g * HD;
  const bf16* kvVt = Vt + ((size_t)(b * NKV + g) * HD) * SEQ;
  int koff[4];
  bf16* kdst[4];
#pragma unroll
  for (int i = 0; i < 4; ++i) {
    int t = i * 256 + tid;          // 1024 K slots of 8 bf16
    int row = t >> 4, c = t & 15;
    int sc = c ^ (row & 7);         // pre-swizzled source chunk
    koff[i] = row * QKVD + sc * 8;
    kdst[i] = Klds + t * 8;
  }
  int voff[4];
  bf16* vdst[4];
#pragma unroll
  for (int i = 0; i < 4; ++i) {
    int t = i * 256 + tid;          // 1024 V slots of 8 bf16
    int d = t >> 3, c = t & 7;
    int sc = c ^ (d & 7);
    voff[i] = d * SEQ + sc * 8;
    vdst[i] = Vlds + t * 8;
  }

  bf16* pb = Plds[w];

#pragma unroll 1
  for (int pass = 0; pass < 2; ++pass) {
    int qt = pass ? (NT - 1 - (int)blockIdx.x) : (int)blockIdx.x;
    int q0 = qt * 64 + w * 16;  // wave's q base

    // --- Q fragments (A operand): rows q0+lr, k = kk*32 + lk*8 + j ---
    bf16x8 aQ[4];
    {
      const bf16* qrow = QKV + ((size_t)(b * SEQ) + q0 + lr) * QKVD + h * HD;
#pragma unroll
      for (int kk = 0; kk < 4; ++kk)
        aQ[kk] = *reinterpret_cast<const bf16x8*>(qrow + kk * 32 + lk * 8);
    }

    f32x4 Oacc[8] = {};
    float m_s[4], l_s[4];
#pragma unroll
    for (int r = 0; r < 4; ++r) { m_s[r] = -1e30f; l_s[r] = 0.f; }

    int jlast = qt * 64;
    for (int j0 = 0; j0 <= jlast; j0 += 64) {
      __syncthreads();  // prev-tile readers done
      {
        const bf16* ks = kvK + (size_t)j0 * QKVD;
        const bf16* vs = kvVt + j0;
#pragma unroll
        for (int i = 0; i < 4; ++i) gload16(ks + koff[i], kdst[i]);
#pragma unroll
        for (int i = 0; i < 4; ++i) gload16(vs + voff[i], vdst[i]);
      }
      __syncthreads();  // staging complete (barrier drains vmcnt)
      if (j0 > q0 + 15) continue;

      // ---- QK^T : 4 n-tiles of 16 cols ----
      f32x4 sc4[4] = {};
#pragma unroll
      for (int kk = 0; kk < 4; ++kk) {
#pragma unroll
        for (int nt = 0; nt < 4; ++nt) {
          int jrow = nt * 16 + lr;
          int pos = (4 * kk + lk) ^ (lr & 7);
          bf16x8 bK = *reinterpret_cast<const bf16x8*>(&Klds[jrow * 128 + pos * 8]);
          sc4[nt] = __builtin_amdgcn_mfma_f32_16x16x32_bf16(aQ[kk], bK, sc4[nt], 0, 0, 0);
        }
      }

      // ---- mask + online softmax (log2 domain) ----
      float sv[4][4], mx[4];
#pragma unroll
      for (int r = 0; r < 4; ++r) mx[r] = -3e38f;
#pragma unroll
      for (int nt = 0; nt < 4; ++nt) {
        int col = j0 + nt * 16 + lr;
#pragma unroll
        for (int r = 0; r < 4; ++r) {
          int row = q0 + lk * 4 + r;
          sv[nt][r] = (col > row) ? -3e38f : sc4[nt][r] * SCALE_LOG2;
          mx[r] = fmaxf(mx[r], sv[nt][r]);
        }
      }
#pragma unroll
      for (int d = 1; d < 16; d <<= 1)
#pragma unroll
        for (int r = 0; r < 4; ++r) mx[r] = fmaxf(mx[r], __shfl_xor(mx[r], d, 64));

      // exact defer-max: rescale only if some row's max grew
      bool grow = false;
#pragma unroll
      for (int r = 0; r < 4; ++r) grow = grow || (mx[r] > m_s[r]);
      if (__any(grow)) {
        float alpha[4];
#pragma unroll
        for (int r = 0; r < 4; ++r) {
          float mn = fmaxf(m_s[r], mx[r]);
          alpha[r] = exp2f(m_s[r] - mn);
          m_s[r] = mn;
          l_s[r] *= alpha[r];
        }
#pragma unroll
        for (int nc = 0; nc < 8; ++nc)
#pragma unroll
          for (int r = 0; r < 4; ++r) Oacc[nc][r] *= alpha[r];
      }
      float p[4][4], rs[4];
#pragma unroll
      for (int r = 0; r < 4; ++r) {
        rs[r] = 0.f;
#pragma unroll
        for (int nt = 0; nt < 4; ++nt) {
          p[nt][r] = exp2f(sv[nt][r] - m_s[r]);
          rs[r] += p[nt][r];
        }
      }
#pragma unroll
      for (int d = 1; d < 16; d <<= 1)
#pragma unroll
        for (int r = 0; r < 4; ++r) rs[r] += __shfl_xor(rs[r], d, 64);
#pragma unroll
      for (int r = 0; r < 4; ++r) l_s[r] += rs[r];

      // ---- P -> wave-private swizzled LDS ----
#pragma unroll
      for (int nt = 0; nt < 4; ++nt)
#pragma unroll
        for (int r = 0; r < 4; ++r) {
          int row = lk * 4 + r;
          int c = nt * 16 + lr;
          pb[row * 64 + (((c >> 3) ^ (row & 7)) * 8) + (c & 7)] = __float2bfloat16(p[nt][r]);
        }
      asm volatile("s_waitcnt lgkmcnt(0)" ::: "memory");
      __builtin_amdgcn_sched_barrier(0);

      // ---- O += P @ V  (V fragments: contiguous bf16x8 along s from Vlds) ----
#pragma unroll
      for (int kb = 0; kb < 2; ++kb) {
        int px = ((kb * 4 + lk) ^ (lr & 7)) * 8;
        bf16x8 aP = *reinterpret_cast<const bf16x8*>(&pb[lr * 64 + px]);
#pragma unroll
        for (int nc = 0; nc < 8; ++nc) {
          bf16x8 bV = *reinterpret_cast<const bf16x8*>(&Vlds[(nc * 16 + lr) * 64 + px]);
          Oacc[nc] = __builtin_amdgcn_mfma_f32_16x16x32_bf16(aP, bV, Oacc[nc], 0, 0, 0);
        }
      }
    }

    // ---- epilogue for this q-tile ----
#pragma unroll
    for (int r = 0; r < 4; ++r) {
      float inv = 1.0f / l_s[r];
      size_t rowoff = ((size_t)(b * SEQ) + q0 + lk * 4 + r) * (NH * HD) + h * HD;
#pragma unroll
      for (int nc = 0; nc < 8; ++nc)
        O[rowoff + nc * 16 + lr] = __float2bfloat16(Oacc[nc][r] * inv);
    }
  }
}

extern "C" void kernel_launch(void* const* d_in, const int* in_sizes, int n_in,
                              void* d_out, int out_size, void* d_ws, size_t ws_size,
                              hipStream_t stream) {
  const float* x = (const float*)d_in[0];
  const float* wq = (const float*)d_in[1];
  const float* wk = (const float*)d_in[2];
  const float* wv = (const float*)d_in[3];
  const float* wo = (const float*)d_in[4];
  const float* fc = (const float*)d_in[5];
  const float* fs = (const float*)d_in[6];
  float* out = (float*)d_out;
  (void)in_sizes; (void)n_in; (void)out_size; (void)ws_size;

  const int R = 2 * SEQ;        // 4096 rows
  const int DIMc = 3072;
  const int NQ = NH * HD;       // 3072

  char* ws = (char*)d_ws;
  bf16* xb = (bf16*)ws;     ws += (size_t)R * DIMc * 2;       // 25.2 MB
  bf16* wqkvT = (bf16*)ws;  ws += (size_t)QKVD * DIMc * 2;    // 31.5 MB
  bf16* woT = (bf16*)ws;    ws += (size_t)DIMc * NQ * 2;      // 18.9 MB
  bf16* QKVb = (bf16*)ws;   ws += (size_t)R * QKVD * 2;       // 41.9 MB
  bf16* Ob = (bf16*)ws;     ws += (size_t)R * NQ * 2;         // 25.2 MB
  bf16* VtG = xb;  // aliases xb: dead after QKV GEMM (needs 8.4 MB)

  // 1) cast x to bf16
  {
    int n4 = R * DIMc / 4;
    cast_f32_bf16<<<n4 / 256, 256, 0, stream>>>(x, xb, n4);
  }
  // 2) transpose+cast weights: wq/wk/wv into fused [5120][3072], wo separate
  transpose_cast<<<dim3(NQ / 32, DIMc / 32), dim3(32, 8), 0, stream>>>(wq, wqkvT, DIMc, NQ);
  transpose_cast<<<dim3(1024 / 32, DIMc / 32), dim3(32, 8), 0, stream>>>(
      wk, wqkvT + (size_t)KOFF * DIMc, DIMc, 1024);
  transpose_cast<<<dim3(1024 / 32, DIMc / 32), dim3(32, 8), 0, stream>>>(
      wv, wqkvT + (size_t)VOFF * DIMc, DIMc, 1024);
  transpose_cast<<<dim3(DIMc / 32, NQ / 32), dim3(32, 8), 0, stream>>>(wo, woT, NQ, DIMc);
  // 3) fused QKV projection: [4096][5120]
  gemm_bt<true><<<dim3(QKVD / 128, R / 128), 256, 0, stream>>>(xb, wqkvT, QKVb, R, QKVD, DIMc);
  // 4) V -> Vt[b][g][d][s]  (xb region; xb dead now)
  transpose_v<<<dim3(SEQ / 32, HD / 32, 2 * NKV), dim3(32, 8), 0, stream>>>(QKVb + VOFF, VtG);
  // 5) RoPE on Q and K regions of QKVb
  {
    int totQ = R * NH * 64;
    rope_kernel<<<totQ / 256, 256, 0, stream>>>(QKVb, fc, fs, NH, QKVD, totQ);
    int totK = R * NKV * 64;
    rope_kernel<<<totK / 256, 256, 0, stream>>>(QKVb + KOFF, fc, fs, NKV, QKVD, totK);
  }
  // 6) attention (balanced q-tile pairs)
  attn_kernel<<<dim3(SEQ / 128, 2 * NH), 256, 0, stream>>>(QKVb, VtG, Ob);
  // 7) output projection -> f32 out
  gemm_bt<false><<<dim3(DIMc / 128, R / 128), 256, 0, stream>>>(Ob, woT, out, R, DIMc, NQ);
}

// Round 7
// 468.852 us; speedup vs baseline: 1.4785x; 1.1072x over previous
//
#include <hip/hip_runtime.h>
#include <hip/hip_bf16.h>

typedef __hip_bfloat16 bf16;
typedef __bf16 bf16x8 __attribute__((ext_vector_type(8)));
typedef float f32x4 __attribute__((ext_vector_type(4)));
typedef short short8 __attribute__((ext_vector_type(8)));

#define NH 24
#define NKV 8
#define HD 128
#define SEQ 2048
#define NREP 3
#define QKVD 5120              // fused QKV row stride (3072 + 1024 + 1024)
#define KOFF 3072              // K region offset in fused row
#define VOFF 4096              // V region offset in fused row

__device__ inline void gload16(const void* g, void* l) {
  __builtin_amdgcn_global_load_lds(
      (const __attribute__((address_space(1))) void*)g,
      (__attribute__((address_space(3))) void*)l, 16, 0, 0);
}

// ---------------- cast f32 -> bf16 (vectorized) ----------------
__global__ void cast_f32_bf16(const float* __restrict__ in, bf16* __restrict__ out, int n4) {
  int i = blockIdx.x * 256 + threadIdx.x;
  if (i >= n4) return;
  float4 v = reinterpret_cast<const float4*>(in)[i];
  ushort4 u;
  u.x = __builtin_bit_cast(unsigned short, __float2bfloat16(v.x));
  u.y = __builtin_bit_cast(unsigned short, __float2bfloat16(v.y));
  u.z = __builtin_bit_cast(unsigned short, __float2bfloat16(v.z));
  u.w = __builtin_bit_cast(unsigned short, __float2bfloat16(v.w));
  reinterpret_cast<ushort4*>(out)[i] = u;
}

// ---------------- transpose + cast: W (KxN f32) -> WT (NxK bf16) ----------------
__global__ void transpose_cast(const float* __restrict__ W, bf16* __restrict__ WT, int K, int N) {
  __shared__ bf16 tile[32][33];
  int n0 = blockIdx.x * 32, k0 = blockIdx.y * 32;
  int tx = threadIdx.x, ty = threadIdx.y;  // (32, 8)
#pragma unroll
  for (int i = 0; i < 4; ++i) {
    int kl = ty + i * 8;
    tile[kl][tx] = __float2bfloat16(W[(size_t)(k0 + kl) * N + n0 + tx]);
  }
  __syncthreads();
#pragma unroll
  for (int i = 0; i < 4; ++i) {
    int nl = ty + i * 8;
    WT[(size_t)(n0 + nl) * K + k0 + tx] = tile[tx][nl];
  }
}

// ---------------- V global transpose: QKV V-region -> Vt[b][g][d][s] ----------------
__global__ void transpose_v(const bf16* __restrict__ Vsrc, bf16* __restrict__ Vt) {
  __shared__ bf16 tile[32][33];
  int bg = blockIdx.z;
  int b = bg >> 3, g = bg & 7;
  int s0 = blockIdx.x * 32, d0 = blockIdx.y * 32;
  int tx = threadIdx.x, ty = threadIdx.y;  // (32, 8)
#pragma unroll
  for (int i = 0; i < 4; ++i) {
    int sl = ty + i * 8;
    tile[sl][tx] = Vsrc[(size_t)(b * SEQ + s0 + sl) * QKVD + g * HD + d0 + tx];
  }
  __syncthreads();
#pragma unroll
  for (int i = 0; i < 4; ++i) {
    int dl = ty + i * 8;
    Vt[((size_t)(b * NKV + g) * HD + d0 + dl) * SEQ + s0 + tx] = tile[tx][dl];
  }
}

// ---------------- RoPE in-place (generalized row stride) ----------------
__global__ void rope_kernel(bf16* __restrict__ T, const float* __restrict__ cosT,
                            const float* __restrict__ sinT, int H, int stride, int total) {
  int i = blockIdx.x * 256 + threadIdx.x;
  if (i >= total) return;
  int d2 = i & 63;
  int rh = i >> 6;
  int r = rh / H;
  int h = rh - r * H;
  int s = r & (SEQ - 1);
  float c = cosT[s * 64 + d2];
  float sn = sinT[s * 64 + d2];
  bf16* p = T + (size_t)r * stride + h * HD + d2 * 2;
  float a = __bfloat162float(p[0]);
  float b = __bfloat162float(p[1]);
  p[0] = __float2bfloat16(a * c - b * sn);
  p[1] = __float2bfloat16(a * sn + b * c);
}

// ---------------- GEMM v2: C[M,N] = A[M,K] @ BT[N,K]^T ----------------
// 128x256 tile, BK=64, 512 threads (8 waves, 2x4), wave-out 64x64.
// LDS: 3 buffers x (A[128][64] + B[256][64]) bf16 = 144 KB (dynamic).
// Both tiles chunk-swizzled: 16B chunk c of row r stored at c^(r&7) (pre-swizzled src).
// Pipeline: 2-tile prefetch distance, counted vmcnt(6), 1 barrier/K-tile.
#define GBUF (24576)  // bf16 elems per buffer: (128+256)*64
template <bool OUT_BF16>
__global__ __launch_bounds__(512, 1) void gemm_bt2(const bf16* __restrict__ A,
                                                   const bf16* __restrict__ BT,
                                                   void* __restrict__ Cv,
                                                   int M, int N, int K, int gx) {
  extern __shared__ __align__(16) bf16 ls[];  // 3 * GBUF
  int nwg = gridDim.x;
  int flat = blockIdx.x;
  int swz = (flat & 7) * (nwg >> 3) + (flat >> 3);  // bijective: nwg % 8 == 0
  int bx = swz % gx, by = swz / gx;
  int m0 = by * 128, n0 = bx * 256;
  int tid = threadIdx.x;
  int w = tid >> 6, lane = tid & 63;
  int wm = w >> 2, wn = w & 3;
  int lr = lane & 15, lk = lane >> 4;

  // staging offsets (pre-swizzled source chunk, linear LDS dest)
  int asrc[2], adst[2];
#pragma unroll
  for (int i = 0; i < 2; ++i) {
    int t = i * 512 + tid;          // 1024 A chunks: row=t>>3 (0..127), c=t&7
    int row = t >> 3, c = t & 7;
    asrc[i] = row * K + ((c ^ (row & 7)) * 8);
    adst[i] = t * 8;
  }
  int bsrc[4], bdst[4];
#pragma unroll
  for (int i = 0; i < 4; ++i) {
    int t = i * 512 + tid;          // 2048 B chunks: row=t>>3 (0..255), c=t&7
    int row = t >> 3, c = t & 7;
    bsrc[i] = row * K + ((c ^ (row & 7)) * 8);
    bdst[i] = 128 * 64 + t * 8;
  }
  const bf16* Ab = A + (size_t)m0 * K;
  const bf16* Bb = BT + (size_t)n0 * K;

  auto STAGE = [&](int kt, int buf) {
    const bf16* a = Ab + kt * 64;
    const bf16* b = Bb + kt * 64;
    bf16* d = ls + buf * GBUF;
#pragma unroll
    for (int i = 0; i < 2; ++i) gload16(a + asrc[i], d + adst[i]);
#pragma unroll
    for (int i = 0; i < 4; ++i) gload16(b + bsrc[i], d + bdst[i]);
  };

  f32x4 acc[4][4] = {};
  const int KT = K >> 6;

  STAGE(0, 0);
  STAGE(1, 1);
  asm volatile("s_waitcnt vmcnt(6)" ::: "memory");  // tile 0 landed; tile 1 in flight
  __builtin_amdgcn_s_barrier();

  for (int kt = 0; kt < KT; ++kt) {
    int nxt = (kt + 2 < KT) ? kt + 2 : KT - 1;      // tail: dummy restage into free buf
    STAGE(nxt, (kt + 2) % 3);

    const bf16* lA = ls + (kt % 3) * GBUF;
    const bf16* lB = lA + 128 * 64;
    bf16x8 bF[4][2];
#pragma unroll
    for (int nt = 0; nt < 4; ++nt)
#pragma unroll
      for (int ks = 0; ks < 2; ++ks)
        bF[nt][ks] = *reinterpret_cast<const bf16x8*>(
            &lB[(wn * 64 + nt * 16 + lr) * 64 + (((ks * 4 + lk) ^ (lr & 7)) * 8)]);
    __builtin_amdgcn_s_setprio(1);
#pragma unroll
    for (int mt = 0; mt < 4; ++mt) {
      int arow = (wm * 64 + mt * 16 + lr) * 64;
      bf16x8 aF0 = *reinterpret_cast<const bf16x8*>(&lA[arow + ((lk ^ (lr & 7)) * 8)]);
      bf16x8 aF1 = *reinterpret_cast<const bf16x8*>(&lA[arow + (((4 + lk) ^ (lr & 7)) * 8)]);
#pragma unroll
      for (int nt = 0; nt < 4; ++nt) {
        acc[mt][nt] = __builtin_amdgcn_mfma_f32_16x16x32_bf16(aF0, bF[nt][0], acc[mt][nt], 0, 0, 0);
        acc[mt][nt] = __builtin_amdgcn_mfma_f32_16x16x32_bf16(aF1, bF[nt][1], acc[mt][nt], 0, 0, 0);
      }
    }
    __builtin_amdgcn_s_setprio(0);
    asm volatile("s_waitcnt vmcnt(6)" ::: "memory");  // tile kt+1's 6 loads landed
    __builtin_amdgcn_sched_barrier(0);
    __builtin_amdgcn_s_barrier();                     // visibility + WAR for buf reuse
  }
  asm volatile("s_waitcnt vmcnt(0)" ::: "memory");    // drain dummy stagings

  // epilogue
#pragma unroll
  for (int mt = 0; mt < 4; ++mt)
#pragma unroll
    for (int nt = 0; nt < 4; ++nt)
#pragma unroll
      for (int r = 0; r < 4; ++r) {
        int m = m0 + wm * 64 + mt * 16 + lk * 4 + r;
        int n = n0 + wn * 64 + nt * 16 + lr;
        float v = acc[mt][nt][r];
        if (OUT_BF16)
          reinterpret_cast<bf16*>(Cv)[(size_t)m * N + n] = __float2bfloat16(v);
        else
          reinterpret_cast<float*>(Cv)[(size_t)m * N + n] = v;
      }
}

// ---------------- Flash attention (causal, GQA, balanced q-tile pairs) ----------------
#define SCALE_LOG2 0.12751745f  // (1/sqrt(128)) * log2(e)

__global__ __launch_bounds__(256, 3) void attn_kernel(const bf16* __restrict__ QKV,
                                                      const bf16* __restrict__ Vt,
                                                      bf16* __restrict__ O) {
  __shared__ bf16 Klds[64 * 128];      // 16 KB
  __shared__ bf16 Vlds[128 * 64];      // 16 KB
  __shared__ bf16 Plds[4][16 * 64];    // 8 KB
  int bh = blockIdx.y;
  int b = bh / NH, h = bh % NH, g = h / NREP;
  int tid = threadIdx.x, w = tid >> 6, lane = tid & 63;
  int lr = lane & 15, lk = lane >> 4;
  const int NT = SEQ / 64;

  const bf16* kvK = QKV + ((size_t)b * SEQ) * QKVD + KOFF + g * HD;
  const bf16* kvVt = Vt + ((size_t)(b * NKV + g) * HD) * SEQ;
  int koff[4];
  bf16* kdst[4];
#pragma unroll
  for (int i = 0; i < 4; ++i) {
    int t = i * 256 + tid;
    int row = t >> 4, c = t & 15;
    int sc = c ^ (row & 7);
    koff[i] = row * QKVD + sc * 8;
    kdst[i] = Klds + t * 8;
  }
  int voff[4];
  bf16* vdst[4];
#pragma unroll
  for (int i = 0; i < 4; ++i) {
    int t = i * 256 + tid;
    int d = t >> 3, c = t & 7;
    int sc = c ^ (d & 7);
    voff[i] = d * SEQ + sc * 8;
    vdst[i] = Vlds + t * 8;
  }

  bf16* pb = Plds[w];

#pragma unroll 1
  for (int pass = 0; pass < 2; ++pass) {
    int qt = pass ? (NT - 1 - (int)blockIdx.x) : (int)blockIdx.x;
    int q0 = qt * 64 + w * 16;

    bf16x8 aQ[4];
    {
      const bf16* qrow = QKV + ((size_t)(b * SEQ) + q0 + lr) * QKVD + h * HD;
#pragma unroll
      for (int kk = 0; kk < 4; ++kk)
        aQ[kk] = *reinterpret_cast<const bf16x8*>(qrow + kk * 32 + lk * 8);
    }

    f32x4 Oacc[8] = {};
    float m_s[4], l_s[4];
#pragma unroll
    for (int r = 0; r < 4; ++r) { m_s[r] = -1e30f; l_s[r] = 0.f; }

    int jlast = qt * 64;
    for (int j0 = 0; j0 <= jlast; j0 += 64) {
      __syncthreads();
      {
        const bf16* ks = kvK + (size_t)j0 * QKVD;
        const bf16* vs = kvVt + j0;
#pragma unroll
        for (int i = 0; i < 4; ++i) gload16(ks + koff[i], kdst[i]);
#pragma unroll
        for (int i = 0; i < 4; ++i) gload16(vs + voff[i], vdst[i]);
      }
      __syncthreads();
      if (j0 > q0 + 15) continue;

      f32x4 sc4[4] = {};
#pragma unroll
      for (int kk = 0; kk < 4; ++kk) {
#pragma unroll
        for (int nt = 0; nt < 4; ++nt) {
          int jrow = nt * 16 + lr;
          int pos = (4 * kk + lk) ^ (lr & 7);
          bf16x8 bK = *reinterpret_cast<const bf16x8*>(&Klds[jrow * 128 + pos * 8]);
          sc4[nt] = __builtin_amdgcn_mfma_f32_16x16x32_bf16(aQ[kk], bK, sc4[nt], 0, 0, 0);
        }
      }

      float sv[4][4], mx[4];
#pragma unroll
      for (int r = 0; r < 4; ++r) mx[r] = -3e38f;
#pragma unroll
      for (int nt = 0; nt < 4; ++nt) {
        int col = j0 + nt * 16 + lr;
#pragma unroll
        for (int r = 0; r < 4; ++r) {
          int row = q0 + lk * 4 + r;
          sv[nt][r] = (col > row) ? -3e38f : sc4[nt][r] * SCALE_LOG2;
          mx[r] = fmaxf(mx[r], sv[nt][r]);
        }
      }
#pragma unroll
      for (int d = 1; d < 16; d <<= 1)
#pragma unroll
        for (int r = 0; r < 4; ++r) mx[r] = fmaxf(mx[r], __shfl_xor(mx[r], d, 64));

      bool grow = false;
#pragma unroll
      for (int r = 0; r < 4; ++r) grow = grow || (mx[r] > m_s[r]);
      if (__any(grow)) {
        float alpha[4];
#pragma unroll
        for (int r = 0; r < 4; ++r) {
          float mn = fmaxf(m_s[r], mx[r]);
          alpha[r] = exp2f(m_s[r] - mn);
          m_s[r] = mn;
          l_s[r] *= alpha[r];
        }
#pragma unroll
        for (int nc = 0; nc < 8; ++nc)
#pragma unroll
          for (int r = 0; r < 4; ++r) Oacc[nc][r] *= alpha[r];
      }
      float p[4][4], rs[4];
#pragma unroll
      for (int r = 0; r < 4; ++r) {
        rs[r] = 0.f;
#pragma unroll
        for (int nt = 0; nt < 4; ++nt) {
          p[nt][r] = exp2f(sv[nt][r] - m_s[r]);
          rs[r] += p[nt][r];
        }
      }
#pragma unroll
      for (int d = 1; d < 16; d <<= 1)
#pragma unroll
        for (int r = 0; r < 4; ++r) rs[r] += __shfl_xor(rs[r], d, 64);
#pragma unroll
      for (int r = 0; r < 4; ++r) l_s[r] += rs[r];

#pragma unroll
      for (int nt = 0; nt < 4; ++nt)
#pragma unroll
        for (int r = 0; r < 4; ++r) {
          int row = lk * 4 + r;
          int c = nt * 16 + lr;
          pb[row * 64 + (((c >> 3) ^ (row & 7)) * 8) + (c & 7)] = __float2bfloat16(p[nt][r]);
        }
      asm volatile("s_waitcnt lgkmcnt(0)" ::: "memory");
      __builtin_amdgcn_sched_barrier(0);

#pragma unroll
      for (int kb = 0; kb < 2; ++kb) {
        int px = ((kb * 4 + lk) ^ (lr & 7)) * 8;
        bf16x8 aP = *reinterpret_cast<const bf16x8*>(&pb[lr * 64 + px]);
#pragma unroll
        for (int nc = 0; nc < 8; ++nc) {
          bf16x8 bV = *reinterpret_cast<const bf16x8*>(&Vlds[(nc * 16 + lr) * 64 + px]);
          Oacc[nc] = __builtin_amdgcn_mfma_f32_16x16x32_bf16(aP, bV, Oacc[nc], 0, 0, 0);
        }
      }
    }

#pragma unroll
    for (int r = 0; r < 4; ++r) {
      float inv = 1.0f / l_s[r];
      size_t rowoff = ((size_t)(b * SEQ) + q0 + lk * 4 + r) * (NH * HD) + h * HD;
#pragma unroll
      for (int nc = 0; nc < 8; ++nc)
        O[rowoff + nc * 16 + lr] = __float2bfloat16(Oacc[nc][r] * inv);
    }
  }
}

extern "C" void kernel_launch(void* const* d_in, const int* in_sizes, int n_in,
                              void* d_out, int out_size, void* d_ws, size_t ws_size,
                              hipStream_t stream) {
  const float* x = (const float*)d_in[0];
  const float* wq = (const float*)d_in[1];
  const float* wk = (const float*)d_in[2];
  const float* wv = (const float*)d_in[3];
  const float* wo = (const float*)d_in[4];
  const float* fc = (const float*)d_in[5];
  const float* fs = (const float*)d_in[6];
  float* out = (float*)d_out;
  (void)in_sizes; (void)n_in; (void)out_size; (void)ws_size;

  const int R = 2 * SEQ;        // 4096 rows
  const int DIMc = 3072;
  const int NQ = NH * HD;       // 3072

  char* ws = (char*)d_ws;
  bf16* xb = (bf16*)ws;     ws += (size_t)R * DIMc * 2;
  bf16* wqkvT = (bf16*)ws;  ws += (size_t)QKVD * DIMc * 2;
  bf16* woT = (bf16*)ws;    ws += (size_t)DIMc * NQ * 2;
  bf16* QKVb = (bf16*)ws;   ws += (size_t)R * QKVD * 2;
  bf16* Ob = (bf16*)ws;     ws += (size_t)R * NQ * 2;
  bf16* VtG = xb;  // aliases xb: dead after QKV GEMM

  const int LDSB = 3 * GBUF * 2;  // 147456 bytes
  hipFuncSetAttribute((const void*)gemm_bt2<true>,
                      hipFuncAttributeMaxDynamicSharedMemorySize, LDSB);
  hipFuncSetAttribute((const void*)gemm_bt2<false>,
                      hipFuncAttributeMaxDynamicSharedMemorySize, LDSB);

  // 1) cast x to bf16
  {
    int n4 = R * DIMc / 4;
    cast_f32_bf16<<<n4 / 256, 256, 0, stream>>>(x, xb, n4);
  }
  // 2) transpose+cast weights
  transpose_cast<<<dim3(NQ / 32, DIMc / 32), dim3(32, 8), 0, stream>>>(wq, wqkvT, DIMc, NQ);
  transpose_cast<<<dim3(1024 / 32, DIMc / 32), dim3(32, 8), 0, stream>>>(
      wk, wqkvT + (size_t)KOFF * DIMc, DIMc, 1024);
  transpose_cast<<<dim3(1024 / 32, DIMc / 32), dim3(32, 8), 0, stream>>>(
      wv, wqkvT + (size_t)VOFF * DIMc, DIMc, 1024);
  transpose_cast<<<dim3(DIMc / 32, NQ / 32), dim3(32, 8), 0, stream>>>(wo, woT, NQ, DIMc);
  // 3) fused QKV projection: [4096][5120] ; grid 20x32 = 640 blocks (%8==0)
  gemm_bt2<true><<<(QKVD / 256) * (R / 128), 512, LDSB, stream>>>(
      xb, wqkvT, QKVb, R, QKVD, DIMc, QKVD / 256);
  // 4) V -> Vt[b][g][d][s]
  transpose_v<<<dim3(SEQ / 32, HD / 32, 2 * NKV), dim3(32, 8), 0, stream>>>(QKVb + VOFF, VtG);
  // 5) RoPE on Q and K regions
  {
    int totQ = R * NH * 64;
    rope_kernel<<<totQ / 256, 256, 0, stream>>>(QKVb, fc, fs, NH, QKVD, totQ);
    int totK = R * NKV * 64;
    rope_kernel<<<totK / 256, 256, 0, stream>>>(QKVb + KOFF, fc, fs, NKV, QKVD, totK);
  }
  // 6) attention
  attn_kernel<<<dim3(SEQ / 128, 2 * NH), 256, 0, stream>>>(QKVb, VtG, Ob);
  // 7) output projection -> f32 out ; grid 12x32 = 384 blocks (%8==0)
  gemm_bt2<false><<<(DIMc / 256) * (R / 128), 512, LDSB, stream>>>(
      Ob, woT, out, R, DIMc, NQ, DIMc / 256);
}

// Round 8
// 463.687 us; speedup vs baseline: 1.4950x; 1.0111x over previous
//
#include <hip/hip_runtime.h>
#include <hip/hip_bf16.h>

typedef __hip_bfloat16 bf16;
typedef __bf16 bf16x8 __attribute__((ext_vector_type(8)));
typedef float f32x4 __attribute__((ext_vector_type(4)));
typedef short short8 __attribute__((ext_vector_type(8)));

#define NH 24
#define NKV 8
#define HD 128
#define SEQ 2048
#define NREP 3
#define QKVD 5120              // fused QKV row stride (3072 + 1024 + 1024)
#define KOFF 3072              // K region offset in fused row
#define VOFF 4096              // V region offset in fused row

__device__ inline void gload16(const void* g, void* l) {
  __builtin_amdgcn_global_load_lds(
      (const __attribute__((address_space(1))) void*)g,
      (__attribute__((address_space(3))) void*)l, 16, 0, 0);
}

// ---------------- cast f32 -> bf16 (vectorized) ----------------
__global__ void cast_f32_bf16(const float* __restrict__ in, bf16* __restrict__ out, int n4) {
  int i = blockIdx.x * 256 + threadIdx.x;
  if (i >= n4) return;
  float4 v = reinterpret_cast<const float4*>(in)[i];
  ushort4 u;
  u.x = __builtin_bit_cast(unsigned short, __float2bfloat16(v.x));
  u.y = __builtin_bit_cast(unsigned short, __float2bfloat16(v.y));
  u.z = __builtin_bit_cast(unsigned short, __float2bfloat16(v.z));
  u.w = __builtin_bit_cast(unsigned short, __float2bfloat16(v.w));
  reinterpret_cast<ushort4*>(out)[i] = u;
}

// ---------------- transpose + cast: W (KxN f32) -> WT (NxK bf16) ----------------
__global__ void transpose_cast(const float* __restrict__ W, bf16* __restrict__ WT, int K, int N) {
  __shared__ bf16 tile[32][33];
  int n0 = blockIdx.x * 32, k0 = blockIdx.y * 32;
  int tx = threadIdx.x, ty = threadIdx.y;  // (32, 8)
#pragma unroll
  for (int i = 0; i < 4; ++i) {
    int kl = ty + i * 8;
    tile[kl][tx] = __float2bfloat16(W[(size_t)(k0 + kl) * N + n0 + tx]);
  }
  __syncthreads();
#pragma unroll
  for (int i = 0; i < 4; ++i) {
    int nl = ty + i * 8;
    WT[(size_t)(n0 + nl) * K + k0 + tx] = tile[tx][nl];
  }
}

// ---------------- V global transpose: QKV V-region -> Vt[b][g][d][s] ----------------
__global__ void transpose_v(const bf16* __restrict__ Vsrc, bf16* __restrict__ Vt) {
  __shared__ bf16 tile[32][33];
  int bg = blockIdx.z;
  int b = bg >> 3, g = bg & 7;
  int s0 = blockIdx.x * 32, d0 = blockIdx.y * 32;
  int tx = threadIdx.x, ty = threadIdx.y;  // (32, 8)
#pragma unroll
  for (int i = 0; i < 4; ++i) {
    int sl = ty + i * 8;
    tile[sl][tx] = Vsrc[(size_t)(b * SEQ + s0 + sl) * QKVD + g * HD + d0 + tx];
  }
  __syncthreads();
#pragma unroll
  for (int i = 0; i < 4; ++i) {
    int dl = ty + i * 8;
    Vt[((size_t)(b * NKV + g) * HD + d0 + dl) * SEQ + s0 + tx] = tile[tx][dl];
  }
}

// ---------------- RoPE in-place (generalized row stride) ----------------
__global__ void rope_kernel(bf16* __restrict__ T, const float* __restrict__ cosT,
                            const float* __restrict__ sinT, int H, int stride, int total) {
  int i = blockIdx.x * 256 + threadIdx.x;
  if (i >= total) return;
  int d2 = i & 63;
  int rh = i >> 6;
  int r = rh / H;
  int h = rh - r * H;
  int s = r & (SEQ - 1);
  float c = cosT[s * 64 + d2];
  float sn = sinT[s * 64 + d2];
  bf16* p = T + (size_t)r * stride + h * HD + d2 * 2;
  float a = __bfloat162float(p[0]);
  float b = __bfloat162float(p[1]);
  p[0] = __float2bfloat16(a * c - b * sn);
  p[1] = __float2bfloat16(a * sn + b * c);
}

// ---------------- GEMM v3: C[M,N] = A[M,K] @ BT[N,K]^T ----------------
// 128x256 tile, BK=32, 256 threads (4 waves 2x2), wave-out 64x128 (32 MFMA : 12 ds_read).
// LDS: 3 buffers x (A[128][32] + B[256][32]) bf16 = 72 KB -> 2 blocks/CU.
// Row = 64B = 4 chunks of 16B; chunk c of row r stored at c^((r>>1)&3) (pre-swizzled
// source, linear gload_lds dest). Bank check (b128, 16 lanes, fixed lk): bank_base
// alternates 0/16 with row parity, chunk XOR cycles every 2 rows -> 8 distinct
// bank-quads over 8 rows -> 2-way aliasing = free (m136).
// Pipeline: distance-2 prefetch, counted vmcnt(6) (6 loads/thread/tile), 1 barrier/tile.
#define GBUF 12288  // bf16 elems per buffer: (128+256)*32
template <bool OUT_BF16>
__global__ __launch_bounds__(256, 2) void gemm_bt2(const bf16* __restrict__ A,
                                                   const bf16* __restrict__ BT,
                                                   void* __restrict__ Cv,
                                                   int M, int N, int K, int gx) {
  extern __shared__ __align__(16) bf16 ls[];  // 3 * GBUF
  int nwg = gridDim.x;
  int flat = blockIdx.x;
  int swz = (flat & 7) * (nwg >> 3) + (flat >> 3);  // bijective: nwg % 8 == 0
  int bx = swz % gx, by = swz / gx;
  int m0 = by * 128, n0 = bx * 256;
  int tid = threadIdx.x;
  int w = tid >> 6, lane = tid & 63;
  int wm = w >> 1, wn = w & 1;
  int lr = lane & 15, lk = lane >> 4;

  // staging offsets (pre-swizzled source chunk, linear LDS dest)
  int asrc[2], adst[2];
#pragma unroll
  for (int i = 0; i < 2; ++i) {
    int t = i * 256 + tid;          // 512 A chunks: row=t>>2 (0..127), c=t&3
    int row = t >> 2, c = t & 3;
    asrc[i] = row * K + ((c ^ ((row >> 1) & 3)) * 8);
    adst[i] = t * 8;
  }
  int bsrc[4], bdst[4];
#pragma unroll
  for (int i = 0; i < 4; ++i) {
    int t = i * 256 + tid;          // 1024 B chunks: row=t>>2 (0..255), c=t&3
    int row = t >> 2, c = t & 3;
    bsrc[i] = row * K + ((c ^ ((row >> 1) & 3)) * 8);
    bdst[i] = 128 * 32 + t * 8;
  }
  const bf16* Ab = A + (size_t)m0 * K;
  const bf16* Bb = BT + (size_t)n0 * K;

  auto STAGE = [&](int kt, int buf) {
    const bf16* a = Ab + kt * 32;
    const bf16* b = Bb + kt * 32;
    bf16* d = ls + buf * GBUF;
#pragma unroll
    for (int i = 0; i < 2; ++i) gload16(a + asrc[i], d + adst[i]);
#pragma unroll
    for (int i = 0; i < 4; ++i) gload16(b + bsrc[i], d + bdst[i]);
  };

  f32x4 acc[4][8] = {};
  const int KT = K >> 5;

  STAGE(0, 0);
  STAGE(1, 1);
  asm volatile("s_waitcnt vmcnt(6)" ::: "memory");  // tile 0 landed; tile 1 in flight
  __builtin_amdgcn_s_barrier();

  for (int kt = 0; kt < KT; ++kt) {
    int nxt = (kt + 2 < KT) ? kt + 2 : KT - 1;      // tail: dummy restage into free buf
    STAGE(nxt, (kt + 2) % 3);

    const bf16* lA = ls + (kt % 3) * GBUF;
    const bf16* lB = lA + 128 * 32;
    bf16x8 aF[4], bF[8];
#pragma unroll
    for (int mt = 0; mt < 4; ++mt) {
      int row = wm * 64 + mt * 16 + lr;
      aF[mt] = *reinterpret_cast<const bf16x8*>(&lA[row * 32 + ((lk ^ ((row >> 1) & 3)) * 8)]);
    }
#pragma unroll
    for (int nt = 0; nt < 8; ++nt) {
      int row = wn * 128 + nt * 16 + lr;
      bF[nt] = *reinterpret_cast<const bf16x8*>(&lB[row * 32 + ((lk ^ ((row >> 1) & 3)) * 8)]);
    }
    __builtin_amdgcn_s_setprio(1);
#pragma unroll
    for (int mt = 0; mt < 4; ++mt)
#pragma unroll
      for (int nt = 0; nt < 8; ++nt)
        acc[mt][nt] = __builtin_amdgcn_mfma_f32_16x16x32_bf16(aF[mt], bF[nt], acc[mt][nt], 0, 0, 0);
    __builtin_amdgcn_s_setprio(0);
    asm volatile("s_waitcnt vmcnt(6)" ::: "memory");  // tile kt+1's 6 loads landed
    __builtin_amdgcn_sched_barrier(0);
    __builtin_amdgcn_s_barrier();                     // visibility + WAR for buf reuse
  }
  asm volatile("s_waitcnt vmcnt(0)" ::: "memory");    // drain dummy stagings

  // epilogue
#pragma unroll
  for (int mt = 0; mt < 4; ++mt)
#pragma unroll
    for (int nt = 0; nt < 8; ++nt)
#pragma unroll
      for (int r = 0; r < 4; ++r) {
        int m = m0 + wm * 64 + mt * 16 + lk * 4 + r;
        int n = n0 + wn * 128 + nt * 16 + lr;
        float v = acc[mt][nt][r];
        if (OUT_BF16)
          reinterpret_cast<bf16*>(Cv)[(size_t)m * N + n] = __float2bfloat16(v);
        else
          reinterpret_cast<float*>(Cv)[(size_t)m * N + n] = v;
      }
}

// ---------------- Flash attention (causal, GQA, balanced q-tile pairs) ----------------
#define SCALE_LOG2 0.12751745f  // (1/sqrt(128)) * log2(e)

__global__ __launch_bounds__(256, 3) void attn_kernel(const bf16* __restrict__ QKV,
                                                      const bf16* __restrict__ Vt,
                                                      bf16* __restrict__ O) {
  __shared__ bf16 Klds[64 * 128];      // 16 KB
  __shared__ bf16 Vlds[128 * 64];      // 16 KB
  __shared__ bf16 Plds[4][16 * 64];    // 8 KB
  int bh = blockIdx.y;
  int b = bh / NH, h = bh % NH, g = h / NREP;
  int tid = threadIdx.x, w = tid >> 6, lane = tid & 63;
  int lr = lane & 15, lk = lane >> 4;
  const int NT = SEQ / 64;

  const bf16* kvK = QKV + ((size_t)b * SEQ) * QKVD + KOFF + g * HD;
  const bf16* kvVt = Vt + ((size_t)(b * NKV + g) * HD) * SEQ;
  int koff[4];
  bf16* kdst[4];
#pragma unroll
  for (int i = 0; i < 4; ++i) {
    int t = i * 256 + tid;
    int row = t >> 4, c = t & 15;
    int sc = c ^ (row & 7);
    koff[i] = row * QKVD + sc * 8;
    kdst[i] = Klds + t * 8;
  }
  int voff[4];
  bf16* vdst[4];
#pragma unroll
  for (int i = 0; i < 4; ++i) {
    int t = i * 256 + tid;
    int d = t >> 3, c = t & 7;
    int sc = c ^ (d & 7);
    voff[i] = d * SEQ + sc * 8;
    vdst[i] = Vlds + t * 8;
  }

  bf16* pb = Plds[w];

#pragma unroll 1
  for (int pass = 0; pass < 2; ++pass) {
    int qt = pass ? (NT - 1 - (int)blockIdx.x) : (int)blockIdx.x;
    int q0 = qt * 64 + w * 16;

    bf16x8 aQ[4];
    {
      const bf16* qrow = QKV + ((size_t)(b * SEQ) + q0 + lr) * QKVD + h * HD;
#pragma unroll
      for (int kk = 0; kk < 4; ++kk)
        aQ[kk] = *reinterpret_cast<const bf16x8*>(qrow + kk * 32 + lk * 8);
    }

    f32x4 Oacc[8] = {};
    float m_s[4], l_s[4];
#pragma unroll
    for (int r = 0; r < 4; ++r) { m_s[r] = -1e30f; l_s[r] = 0.f; }

    int jlast = qt * 64;
    for (int j0 = 0; j0 <= jlast; j0 += 64) {
      __syncthreads();
      {
        const bf16* ks = kvK + (size_t)j0 * QKVD;
        const bf16* vs = kvVt + j0;
#pragma unroll
        for (int i = 0; i < 4; ++i) gload16(ks + koff[i], kdst[i]);
#pragma unroll
        for (int i = 0; i < 4; ++i) gload16(vs + voff[i], vdst[i]);
      }
      __syncthreads();
      if (j0 > q0 + 15) continue;

      f32x4 sc4[4] = {};
#pragma unroll
      for (int kk = 0; kk < 4; ++kk) {
#pragma unroll
        for (int nt = 0; nt < 4; ++nt) {
          int jrow = nt * 16 + lr;
          int pos = (4 * kk + lk) ^ (lr & 7);
          bf16x8 bK = *reinterpret_cast<const bf16x8*>(&Klds[jrow * 128 + pos * 8]);
          sc4[nt] = __builtin_amdgcn_mfma_f32_16x16x32_bf16(aQ[kk], bK, sc4[nt], 0, 0, 0);
        }
      }

      float sv[4][4], mx[4];
#pragma unroll
      for (int r = 0; r < 4; ++r) mx[r] = -3e38f;
#pragma unroll
      for (int nt = 0; nt < 4; ++nt) {
        int col = j0 + nt * 16 + lr;
#pragma unroll
        for (int r = 0; r < 4; ++r) {
          int row = q0 + lk * 4 + r;
          sv[nt][r] = (col > row) ? -3e38f : sc4[nt][r] * SCALE_LOG2;
          mx[r] = fmaxf(mx[r], sv[nt][r]);
        }
      }
#pragma unroll
      for (int d = 1; d < 16; d <<= 1)
#pragma unroll
        for (int r = 0; r < 4; ++r) mx[r] = fmaxf(mx[r], __shfl_xor(mx[r], d, 64));

      bool grow = false;
#pragma unroll
      for (int r = 0; r < 4; ++r) grow = grow || (mx[r] > m_s[r]);
      if (__any(grow)) {
        float alpha[4];
#pragma unroll
        for (int r = 0; r < 4; ++r) {
          float mn = fmaxf(m_s[r], mx[r]);
          alpha[r] = exp2f(m_s[r] - mn);
          m_s[r] = mn;
          l_s[r] *= alpha[r];
        }
#pragma unroll
        for (int nc = 0; nc < 8; ++nc)
#pragma unroll
          for (int r = 0; r < 4; ++r) Oacc[nc][r] *= alpha[r];
      }
      float p[4][4], rs[4];
#pragma unroll
      for (int r = 0; r < 4; ++r) {
        rs[r] = 0.f;
#pragma unroll
        for (int nt = 0; nt < 4; ++nt) {
          p[nt][r] = exp2f(sv[nt][r] - m_s[r]);
          rs[r] += p[nt][r];
        }
      }
#pragma unroll
      for (int d = 1; d < 16; d <<= 1)
#pragma unroll
        for (int r = 0; r < 4; ++r) rs[r] += __shfl_xor(rs[r], d, 64);
#pragma unroll
      for (int r = 0; r < 4; ++r) l_s[r] += rs[r];

#pragma unroll
      for (int nt = 0; nt < 4; ++nt)
#pragma unroll
        for (int r = 0; r < 4; ++r) {
          int row = lk * 4 + r;
          int c = nt * 16 + lr;
          pb[row * 64 + (((c >> 3) ^ (row & 7)) * 8) + (c & 7)] = __float2bfloat16(p[nt][r]);
        }
      asm volatile("s_waitcnt lgkmcnt(0)" ::: "memory");
      __builtin_amdgcn_sched_barrier(0);

#pragma unroll
      for (int kb = 0; kb < 2; ++kb) {
        int px = ((kb * 4 + lk) ^ (lr & 7)) * 8;
        bf16x8 aP = *reinterpret_cast<const bf16x8*>(&pb[lr * 64 + px]);
#pragma unroll
        for (int nc = 0; nc < 8; ++nc) {
          bf16x8 bV = *reinterpret_cast<const bf16x8*>(&Vlds[(nc * 16 + lr) * 64 + px]);
          Oacc[nc] = __builtin_amdgcn_mfma_f32_16x16x32_bf16(aP, bV, Oacc[nc], 0, 0, 0);
        }
      }
    }

#pragma unroll
    for (int r = 0; r < 4; ++r) {
      float inv = 1.0f / l_s[r];
      size_t rowoff = ((size_t)(b * SEQ) + q0 + lk * 4 + r) * (NH * HD) + h * HD;
#pragma unroll
      for (int nc = 0; nc < 8; ++nc)
        O[rowoff + nc * 16 + lr] = __float2bfloat16(Oacc[nc][r] * inv);
    }
  }
}

extern "C" void kernel_launch(void* const* d_in, const int* in_sizes, int n_in,
                              void* d_out, int out_size, void* d_ws, size_t ws_size,
                              hipStream_t stream) {
  const float* x = (const float*)d_in[0];
  const float* wq = (const float*)d_in[1];
  const float* wk = (const float*)d_in[2];
  const float* wv = (const float*)d_in[3];
  const float* wo = (const float*)d_in[4];
  const float* fc = (const float*)d_in[5];
  const float* fs = (const float*)d_in[6];
  float* out = (float*)d_out;
  (void)in_sizes; (void)n_in; (void)out_size; (void)ws_size;

  const int R = 2 * SEQ;        // 4096 rows
  const int DIMc = 3072;
  const int NQ = NH * HD;       // 3072

  char* ws = (char*)d_ws;
  bf16* xb = (bf16*)ws;     ws += (size_t)R * DIMc * 2;
  bf16* wqkvT = (bf16*)ws;  ws += (size_t)QKVD * DIMc * 2;
  bf16* woT = (bf16*)ws;    ws += (size_t)DIMc * NQ * 2;
  bf16* QKVb = (bf16*)ws;   ws += (size_t)R * QKVD * 2;
  bf16* Ob = (bf16*)ws;     ws += (size_t)R * NQ * 2;
  bf16* VtG = xb;  // aliases xb: dead after QKV GEMM

  const int LDSB = 3 * GBUF * 2;  // 73728 bytes
  hipFuncSetAttribute((const void*)gemm_bt2<true>,
                      hipFuncAttributeMaxDynamicSharedMemorySize, LDSB);
  hipFuncSetAttribute((const void*)gemm_bt2<false>,
                      hipFuncAttributeMaxDynamicSharedMemorySize, LDSB);

  // 1) cast x to bf16
  {
    int n4 = R * DIMc / 4;
    cast_f32_bf16<<<n4 / 256, 256, 0, stream>>>(x, xb, n4);
  }
  // 2) transpose+cast weights
  transpose_cast<<<dim3(NQ / 32, DIMc / 32), dim3(32, 8), 0, stream>>>(wq, wqkvT, DIMc, NQ);
  transpose_cast<<<dim3(1024 / 32, DIMc / 32), dim3(32, 8), 0, stream>>>(
      wk, wqkvT + (size_t)KOFF * DIMc, DIMc, 1024);
  transpose_cast<<<dim3(1024 / 32, DIMc / 32), dim3(32, 8), 0, stream>>>(
      wv, wqkvT + (size_t)VOFF * DIMc, DIMc, 1024);
  transpose_cast<<<dim3(DIMc / 32, NQ / 32), dim3(32, 8), 0, stream>>>(wo, woT, NQ, DIMc);
  // 3) fused QKV projection: [4096][5120] ; grid 20x32 = 640 blocks (%8==0)
  gemm_bt2<true><<<(QKVD / 256) * (R / 128), 256, LDSB, stream>>>(
      xb, wqkvT, QKVb, R, QKVD, DIMc, QKVD / 256);
  // 4) V -> Vt[b][g][d][s]
  transpose_v<<<dim3(SEQ / 32, HD / 32, 2 * NKV), dim3(32, 8), 0, stream>>>(QKVb + VOFF, VtG);
  // 5) RoPE on Q and K regions
  {
    int totQ = R * NH * 64;
    rope_kernel<<<totQ / 256, 256, 0, stream>>>(QKVb, fc, fs, NH, QKVD, totQ);
    int totK = R * NKV * 64;
    rope_kernel<<<totK / 256, 256, 0, stream>>>(QKVb + KOFF, fc, fs, NKV, QKVD, totK);
  }
  // 6) attention
  attn_kernel<<<dim3(SEQ / 128, 2 * NH), 256, 0, stream>>>(QKVb, VtG, Ob);
  // 7) output projection -> f32 out ; grid 12x32 = 384 blocks (%8==0)
  gemm_bt2<false><<<(DIMc / 256) * (R / 128), 256, LDSB, stream>>>(
      Ob, woT, out, R, DIMc, NQ, DIMc / 256);
}

// Round 9
// 454.432 us; speedup vs baseline: 1.5254x; 1.0204x over previous
//
#include <hip/hip_runtime.h>
#include <hip/hip_bf16.h>

typedef __hip_bfloat16 bf16;
typedef __bf16 bf16x8 __attribute__((ext_vector_type(8)));
typedef float f32x4 __attribute__((ext_vector_type(4)));
typedef short short8 __attribute__((ext_vector_type(8)));

#define NH 24
#define NKV 8
#define HD 128
#define SEQ 2048
#define NREP 3
#define QKVD 5120              // fused QKV row stride (3072 + 1024 + 1024)
#define KOFF 3072              // K region offset in fused row
#define VOFF 4096              // V region offset in fused row

__device__ inline void gload16(const void* g, void* l) {
  __builtin_amdgcn_global_load_lds(
      (const __attribute__((address_space(1))) void*)g,
      (__attribute__((address_space(3))) void*)l, 16, 0, 0);
}

// ---------------- cast f32 -> bf16 (vectorized) ----------------
__global__ void cast_f32_bf16(const float* __restrict__ in, bf16* __restrict__ out, int n4) {
  int i = blockIdx.x * 256 + threadIdx.x;
  if (i >= n4) return;
  float4 v = reinterpret_cast<const float4*>(in)[i];
  ushort4 u;
  u.x = __builtin_bit_cast(unsigned short, __float2bfloat16(v.x));
  u.y = __builtin_bit_cast(unsigned short, __float2bfloat16(v.y));
  u.z = __builtin_bit_cast(unsigned short, __float2bfloat16(v.z));
  u.w = __builtin_bit_cast(unsigned short, __float2bfloat16(v.w));
  reinterpret_cast<ushort4*>(out)[i] = u;
}

// ---------------- transpose + cast: W (KxN f32) -> WT (NxK bf16) ----------------
__global__ void transpose_cast(const float* __restrict__ W, bf16* __restrict__ WT, int K, int N) {
  __shared__ bf16 tile[32][33];
  int n0 = blockIdx.x * 32, k0 = blockIdx.y * 32;
  int tx = threadIdx.x, ty = threadIdx.y;  // (32, 8)
#pragma unroll
  for (int i = 0; i < 4; ++i) {
    int kl = ty + i * 8;
    tile[kl][tx] = __float2bfloat16(W[(size_t)(k0 + kl) * N + n0 + tx]);
  }
  __syncthreads();
#pragma unroll
  for (int i = 0; i < 4; ++i) {
    int nl = ty + i * 8;
    WT[(size_t)(n0 + nl) * K + k0 + tx] = tile[tx][nl];
  }
}

// ---------------- V global transpose: QKV V-region -> Vt[b][g][d][s] ----------------
__global__ void transpose_v(const bf16* __restrict__ Vsrc, bf16* __restrict__ Vt) {
  __shared__ bf16 tile[32][33];
  int bg = blockIdx.z;
  int b = bg >> 3, g = bg & 7;
  int s0 = blockIdx.x * 32, d0 = blockIdx.y * 32;
  int tx = threadIdx.x, ty = threadIdx.y;  // (32, 8)
#pragma unroll
  for (int i = 0; i < 4; ++i) {
    int sl = ty + i * 8;
    tile[sl][tx] = Vsrc[(size_t)(b * SEQ + s0 + sl) * QKVD + g * HD + d0 + tx];
  }
  __syncthreads();
#pragma unroll
  for (int i = 0; i < 4; ++i) {
    int dl = ty + i * 8;
    Vt[((size_t)(b * NKV + g) * HD + d0 + dl) * SEQ + s0 + tx] = tile[tx][dl];
  }
}

// ---------------- RoPE in-place (generalized row stride) ----------------
__global__ void rope_kernel(bf16* __restrict__ T, const float* __restrict__ cosT,
                            const float* __restrict__ sinT, int H, int stride, int total) {
  int i = blockIdx.x * 256 + threadIdx.x;
  if (i >= total) return;
  int d2 = i & 63;
  int rh = i >> 6;
  int r = rh / H;
  int h = rh - r * H;
  int s = r & (SEQ - 1);
  float c = cosT[s * 64 + d2];
  float sn = sinT[s * 64 + d2];
  bf16* p = T + (size_t)r * stride + h * HD + d2 * 2;
  float a = __bfloat162float(p[0]);
  float b = __bfloat162float(p[1]);
  p[0] = __float2bfloat16(a * c - b * sn);
  p[1] = __float2bfloat16(a * sn + b * c);
}

// ---------------- GEMM v4: 256x256 tile, 8-phase schedule (m201 template) ----------------
// 512 threads = 8 waves (2M x 4N), wave-out 128x64, acc[8][4], BK=64 as 2 k-halves of 32.
// LDS: 4 half-slots x (A[256][32] + B[256][32]) = 128 KB. slot = buf*2 + h; buf0=even kt.
// Swizzle (R8-verified, 0 conflicts): 16B chunk c of row r stored at c^((r>>1)&3),
// pre-swizzled global source + linear gload_lds dest; reads apply same XOR.
// Per phase: {ds_read 4-8 frags | stage 2 gload16} bar; lgkmcnt0; prio1; 16 MFMA; prio0; bar.
// vmcnt(4) only at end of phases 4 & 8 (12 outstanding -> 4): next K-tile fully landed.
#define SLOT_E 16384   // bf16 elems per half-slot (A 8192 + B 8192)
template <bool OUT_BF16>
__global__ __launch_bounds__(512, 1) void gemm_bt3(const bf16* __restrict__ A,
                                                   const bf16* __restrict__ BT,
                                                   void* __restrict__ Cv,
                                                   int M, int N, int K, int gx) {
  extern __shared__ __align__(16) bf16 ls[];  // 4 * SLOT_E
  int nwg = gridDim.x;
  int flat = blockIdx.x;
  int swz = (flat & 7) * (nwg >> 3) + (flat >> 3);  // bijective: nwg % 8 == 0
  int bx = swz % gx, by = swz / gx;
  int m0 = by * 256, n0 = bx * 256;
  int tid = threadIdx.x, w = tid >> 6, lane = tid & 63;
  int wm = w >> 2, wn = w & 3;
  int lr = lane & 15, lk = lane >> 4;

  // staging: one unit = 256 rows x 32 cols (16 KB) = 1024 chunks; 2 chunks/thread
  int soff[2], sdst[2];
#pragma unroll
  for (int i = 0; i < 2; ++i) {
    int t = i * 512 + tid;
    int row = t >> 2, c = t & 3;
    soff[i] = row * K + ((c ^ ((row >> 1) & 3)) * 8);
    sdst[i] = t * 8;
  }
  const bf16* Ab = A + (size_t)m0 * K;
  const bf16* Bb = BT + (size_t)n0 * K;

  auto STAGE = [&](const bf16* base, int kt, int h, int slot, int op) {
    const bf16* s = base + kt * 64 + h * 32;
    bf16* d = ls + slot * SLOT_E + op * 8192;
#pragma unroll
    for (int i = 0; i < 2; ++i) gload16(s + soff[i], d + sdst[i]);
  };

  f32x4 acc[8][4] = {};
  bf16x8 aF[4], bF[4];

  // fragment loads (slot = buf*2 + ks)
  auto LDA = [&](int slot, int mh) {
    const bf16* base = ls + slot * SLOT_E;
#pragma unroll
    for (int mt = 0; mt < 4; ++mt) {
      int row = wm * 128 + (mh * 4 + mt) * 16 + lr;
      aF[mt] = *reinterpret_cast<const bf16x8*>(&base[row * 32 + ((lk ^ ((row >> 1) & 3)) * 8)]);
    }
  };
  auto LDB = [&](int slot) {
    const bf16* base = ls + slot * SLOT_E + 8192;
#pragma unroll
    for (int nt = 0; nt < 4; ++nt) {
      int row = wn * 64 + nt * 16 + lr;
      bF[nt] = *reinterpret_cast<const bf16x8*>(&base[row * 32 + ((lk ^ ((row >> 1) & 3)) * 8)]);
    }
  };

#define PHASE(CSLOT, MH, SBASE, SKT, SH, SSLOT, SOP, WAITN)                         \
  {                                                                                 \
    __builtin_amdgcn_sched_barrier(0);                                              \
    if (MH == 0) LDB(CSLOT);                                                        \
    LDA(CSLOT, MH);                                                                 \
    STAGE(SBASE, SKT, SH, SSLOT, SOP);                                              \
    __builtin_amdgcn_s_barrier();                                                   \
    asm volatile("s_waitcnt lgkmcnt(0)" ::: "memory");                              \
    __builtin_amdgcn_sched_barrier(0);                                              \
    __builtin_amdgcn_s_setprio(1);                                                  \
    _Pragma("unroll") for (int mt = 0; mt < 4; ++mt)                                \
        _Pragma("unroll") for (int nt = 0; nt < 4; ++nt)                            \
            acc[MH * 4 + mt][nt] =                                                  \
        __builtin_amdgcn_mfma_f32_16x16x32_bf16(aF[mt], bF[nt], acc[MH * 4 + mt][nt], 0, 0, 0); \
    __builtin_amdgcn_s_setprio(0);                                                  \
    if (WAITN >= 0) asm volatile("s_waitcnt vmcnt(4)" ::: "memory");                \
    __builtin_amdgcn_sched_barrier(0);                                              \
    __builtin_amdgcn_s_barrier();                                                   \
  }

  const int KT = K >> 6;       // 64-wide K-tiles (even; K=3072 -> 48)
  const int IT = KT >> 1;

  // prologue: kt0.h0 -> slot0, kt0.h1 -> slot1, kt1.h0 -> slot2 (12 loads)
  STAGE(Ab, 0, 0, 0, 0); STAGE(Bb, 0, 0, 0, 1);
  STAGE(Ab, 0, 1, 1, 0); STAGE(Bb, 0, 1, 1, 1);
  STAGE(Ab, 1, 0, 2, 0); STAGE(Bb, 1, 0, 2, 1);
  asm volatile("s_waitcnt vmcnt(4)" ::: "memory");  // kt0 fully landed
  __builtin_amdgcn_s_barrier();

  for (int j = 0; j < IT; ++j) {
    int k1 = 2 * j + 1;
    int k2 = 2 * j + 2 < KT ? 2 * j + 2 : KT - 1;   // tail: dummy restage
    int k3 = 2 * j + 3 < KT ? 2 * j + 3 : KT - 1;
    // K-tile 2j in slots 0 (ks0) / 1 (ks1)
    PHASE(0, 0, Ab, k1, 1, 3, 0, -1)   // P1: stage A(k1.h1)->slot3 (dead since prev P7)
    PHASE(0, 1, Bb, k1, 1, 3, 1, -1)   // P2
    PHASE(1, 0, Ab, k2, 0, 0, 0, -1)   // P3: slot0 dead after P2
    PHASE(1, 1, Bb, k2, 0, 0, 1, 4)    // P4 + vmcnt: kt(2j+1) fully landed
    // K-tile 2j+1 in slots 2 (ks0) / 3 (ks1)
    PHASE(2, 0, Ab, k2, 1, 1, 0, -1)   // P5: slot1 dead after P4
    PHASE(2, 1, Bb, k2, 1, 1, 1, -1)   // P6
    PHASE(3, 0, Ab, k3, 0, 2, 0, -1)   // P7: slot2 dead after P6
    PHASE(3, 1, Bb, k3, 0, 2, 1, 4)    // P8 + vmcnt: kt(2j+2) fully landed
  }
  asm volatile("s_waitcnt vmcnt(0)" ::: "memory");  // drain dummy stagings
#undef PHASE

  // epilogue
#pragma unroll
  for (int fr = 0; fr < 8; ++fr)
#pragma unroll
    for (int nt = 0; nt < 4; ++nt)
#pragma unroll
      for (int r = 0; r < 4; ++r) {
        int m = m0 + wm * 128 + fr * 16 + lk * 4 + r;
        int n = n0 + wn * 64 + nt * 16 + lr;
        float v = acc[fr][nt][r];
        if (OUT_BF16)
          reinterpret_cast<bf16*>(Cv)[(size_t)m * N + n] = __float2bfloat16(v);
        else
          reinterpret_cast<float*>(Cv)[(size_t)m * N + n] = v;
      }
}

// ---------------- Flash attention (causal, GQA, balanced q-tile pairs) ----------------
#define SCALE_LOG2 0.12751745f  // (1/sqrt(128)) * log2(e)

__global__ __launch_bounds__(256, 3) void attn_kernel(const bf16* __restrict__ QKV,
                                                      const bf16* __restrict__ Vt,
                                                      bf16* __restrict__ O) {
  __shared__ bf16 Klds[64 * 128];      // 16 KB
  __shared__ bf16 Vlds[128 * 64];      // 16 KB
  __shared__ bf16 Plds[4][16 * 64];    // 8 KB
  int bh = blockIdx.y;
  int b = bh / NH, h = bh % NH, g = h / NREP;
  int tid = threadIdx.x, w = tid >> 6, lane = tid & 63;
  int lr = lane & 15, lk = lane >> 4;
  const int NT = SEQ / 64;

  const bf16* kvK = QKV + ((size_t)b * SEQ) * QKVD + KOFF + g * HD;
  const bf16* kvVt = Vt + ((size_t)(b * NKV + g) * HD) * SEQ;
  int koff[4];
  bf16* kdst[4];
#pragma unroll
  for (int i = 0; i < 4; ++i) {
    int t = i * 256 + tid;
    int row = t >> 4, c = t & 15;
    int sc = c ^ (row & 7);
    koff[i] = row * QKVD + sc * 8;
    kdst[i] = Klds + t * 8;
  }
  int voff[4];
  bf16* vdst[4];
#pragma unroll
  for (int i = 0; i < 4; ++i) {
    int t = i * 256 + tid;
    int d = t >> 3, c = t & 7;
    int sc = c ^ (d & 7);
    voff[i] = d * SEQ + sc * 8;
    vdst[i] = Vlds + t * 8;
  }

  bf16* pb = Plds[w];

#pragma unroll 1
  for (int pass = 0; pass < 2; ++pass) {
    int qt = pass ? (NT - 1 - (int)blockIdx.x) : (int)blockIdx.x;
    int q0 = qt * 64 + w * 16;

    bf16x8 aQ[4];
    {
      const bf16* qrow = QKV + ((size_t)(b * SEQ) + q0 + lr) * QKVD + h * HD;
#pragma unroll
      for (int kk = 0; kk < 4; ++kk)
        aQ[kk] = *reinterpret_cast<const bf16x8*>(qrow + kk * 32 + lk * 8);
    }

    f32x4 Oacc[8] = {};
    float m_s[4], l_s[4];
#pragma unroll
    for (int r = 0; r < 4; ++r) { m_s[r] = -1e30f; l_s[r] = 0.f; }

    int jlast = qt * 64;
    for (int j0 = 0; j0 <= jlast; j0 += 64) {
      __syncthreads();
      {
        const bf16* ks = kvK + (size_t)j0 * QKVD;
        const bf16* vs = kvVt + j0;
#pragma unroll
        for (int i = 0; i < 4; ++i) gload16(ks + koff[i], kdst[i]);
#pragma unroll
        for (int i = 0; i < 4; ++i) gload16(vs + voff[i], vdst[i]);
      }
      __syncthreads();
      if (j0 > q0 + 15) continue;

      f32x4 sc4[4] = {};
#pragma unroll
      for (int kk = 0; kk < 4; ++kk) {
#pragma unroll
        for (int nt = 0; nt < 4; ++nt) {
          int jrow = nt * 16 + lr;
          int pos = (4 * kk + lk) ^ (lr & 7);
          bf16x8 bK = *reinterpret_cast<const bf16x8*>(&Klds[jrow * 128 + pos * 8]);
          sc4[nt] = __builtin_amdgcn_mfma_f32_16x16x32_bf16(aQ[kk], bK, sc4[nt], 0, 0, 0);
        }
      }

      float sv[4][4], mx[4];
#pragma unroll
      for (int r = 0; r < 4; ++r) mx[r] = -3e38f;
#pragma unroll
      for (int nt = 0; nt < 4; ++nt) {
        int col = j0 + nt * 16 + lr;
#pragma unroll
        for (int r = 0; r < 4; ++r) {
          int row = q0 + lk * 4 + r;
          sv[nt][r] = (col > row) ? -3e38f : sc4[nt][r] * SCALE_LOG2;
          mx[r] = fmaxf(mx[r], sv[nt][r]);
        }
      }
#pragma unroll
      for (int d = 1; d < 16; d <<= 1)
#pragma unroll
        for (int r = 0; r < 4; ++r) mx[r] = fmaxf(mx[r], __shfl_xor(mx[r], d, 64));

      bool grow = false;
#pragma unroll
      for (int r = 0; r < 4; ++r) grow = grow || (mx[r] > m_s[r]);
      if (__any(grow)) {
        float alpha[4];
#pragma unroll
        for (int r = 0; r < 4; ++r) {
          float mn = fmaxf(m_s[r], mx[r]);
          alpha[r] = exp2f(m_s[r] - mn);
          m_s[r] = mn;
          l_s[r] *= alpha[r];
        }
#pragma unroll
        for (int nc = 0; nc < 8; ++nc)
#pragma unroll
          for (int r = 0; r < 4; ++r) Oacc[nc][r] *= alpha[r];
      }
      float p[4][4], rs[4];
#pragma unroll
      for (int r = 0; r < 4; ++r) {
        rs[r] = 0.f;
#pragma unroll
        for (int nt = 0; nt < 4; ++nt) {
          p[nt][r] = exp2f(sv[nt][r] - m_s[r]);
          rs[r] += p[nt][r];
        }
      }
#pragma unroll
      for (int d = 1; d < 16; d <<= 1)
#pragma unroll
        for (int r = 0; r < 4; ++r) rs[r] += __shfl_xor(rs[r], d, 64);
#pragma unroll
      for (int r = 0; r < 4; ++r) l_s[r] += rs[r];

#pragma unroll
      for (int nt = 0; nt < 4; ++nt)
#pragma unroll
        for (int r = 0; r < 4; ++r) {
          int row = lk * 4 + r;
          int c = nt * 16 + lr;
          pb[row * 64 + (((c >> 3) ^ (row & 7)) * 8) + (c & 7)] = __float2bfloat16(p[nt][r]);
        }
      asm volatile("s_waitcnt lgkmcnt(0)" ::: "memory");
      __builtin_amdgcn_sched_barrier(0);

#pragma unroll
      for (int kb = 0; kb < 2; ++kb) {
        int px = ((kb * 4 + lk) ^ (lr & 7)) * 8;
        bf16x8 aP = *reinterpret_cast<const bf16x8*>(&pb[lr * 64 + px]);
#pragma unroll
        for (int nc = 0; nc < 8; ++nc) {
          bf16x8 bV = *reinterpret_cast<const bf16x8*>(&Vlds[(nc * 16 + lr) * 64 + px]);
          Oacc[nc] = __builtin_amdgcn_mfma_f32_16x16x32_bf16(aP, bV, Oacc[nc], 0, 0, 0);
        }
      }
    }

#pragma unroll
    for (int r = 0; r < 4; ++r) {
      float inv = 1.0f / l_s[r];
      size_t rowoff = ((size_t)(b * SEQ) + q0 + lk * 4 + r) * (NH * HD) + h * HD;
#pragma unroll
      for (int nc = 0; nc < 8; ++nc)
        O[rowoff + nc * 16 + lr] = __float2bfloat16(Oacc[nc][r] * inv);
    }
  }
}

extern "C" void kernel_launch(void* const* d_in, const int* in_sizes, int n_in,
                              void* d_out, int out_size, void* d_ws, size_t ws_size,
                              hipStream_t stream) {
  const float* x = (const float*)d_in[0];
  const float* wq = (const float*)d_in[1];
  const float* wk = (const float*)d_in[2];
  const float* wv = (const float*)d_in[3];
  const float* wo = (const float*)d_in[4];
  const float* fc = (const float*)d_in[5];
  const float* fs = (const float*)d_in[6];
  float* out = (float*)d_out;
  (void)in_sizes; (void)n_in; (void)out_size; (void)ws_size;

  const int R = 2 * SEQ;        // 4096 rows
  const int DIMc = 3072;
  const int NQ = NH * HD;       // 3072

  char* ws = (char*)d_ws;
  bf16* xb = (bf16*)ws;     ws += (size_t)R * DIMc * 2;
  bf16* wqkvT = (bf16*)ws;  ws += (size_t)QKVD * DIMc * 2;
  bf16* woT = (bf16*)ws;    ws += (size_t)DIMc * NQ * 2;
  bf16* QKVb = (bf16*)ws;   ws += (size_t)R * QKVD * 2;
  bf16* Ob = (bf16*)ws;     ws += (size_t)R * NQ * 2;
  bf16* VtG = xb;  // aliases xb: dead after QKV GEMM

  const int LDSB = 4 * SLOT_E * 2;  // 131072 bytes
  hipFuncSetAttribute((const void*)gemm_bt3<true>,
                      hipFuncAttributeMaxDynamicSharedMemorySize, LDSB);
  hipFuncSetAttribute((const void*)gemm_bt3<false>,
                      hipFuncAttributeMaxDynamicSharedMemorySize, LDSB);

  // 1) cast x to bf16
  {
    int n4 = R * DIMc / 4;
    cast_f32_bf16<<<n4 / 256, 256, 0, stream>>>(x, xb, n4);
  }
  // 2) transpose+cast weights
  transpose_cast<<<dim3(NQ / 32, DIMc / 32), dim3(32, 8), 0, stream>>>(wq, wqkvT, DIMc, NQ);
  transpose_cast<<<dim3(1024 / 32, DIMc / 32), dim3(32, 8), 0, stream>>>(
      wk, wqkvT + (size_t)KOFF * DIMc, DIMc, 1024);
  transpose_cast<<<dim3(1024 / 32, DIMc / 32), dim3(32, 8), 0, stream>>>(
      wv, wqkvT + (size_t)VOFF * DIMc, DIMc, 1024);
  transpose_cast<<<dim3(DIMc / 32, NQ / 32), dim3(32, 8), 0, stream>>>(wo, woT, NQ, DIMc);
  // 3) fused QKV projection: [4096][5120] ; grid 20x16 = 320 blocks (%8==0)
  gemm_bt3<true><<<(QKVD / 256) * (R / 256), 512, LDSB, stream>>>(
      xb, wqkvT, QKVb, R, QKVD, DIMc, QKVD / 256);
  // 4) V -> Vt[b][g][d][s]
  transpose_v<<<dim3(SEQ / 32, HD / 32, 2 * NKV), dim3(32, 8), 0, stream>>>(QKVb + VOFF, VtG);
  // 5) RoPE on Q and K regions
  {
    int totQ = R * NH * 64;
    rope_kernel<<<totQ / 256, 256, 0, stream>>>(QKVb, fc, fs, NH, QKVD, totQ);
    int totK = R * NKV * 64;
    rope_kernel<<<totK / 256, 256, 0, stream>>>(QKVb + KOFF, fc, fs, NKV, QKVD, totK);
  }
  // 6) attention
  attn_kernel<<<dim3(SEQ / 128, 2 * NH), 256, 0, stream>>>(QKVb, VtG, Ob);
  // 7) output projection -> f32 out ; grid 12x16 = 192 blocks (%8==0)
  gemm_bt3<false><<<(DIMc / 256) * (R / 256), 512, LDSB, stream>>>(
      Ob, woT, out, R, DIMc, NQ, DIMc / 256);
}